// Round 5
// baseline (1519.298 us; speedup 1.0000x reference)
//
#include <hip/hip_runtime.h>
#include <hip/hip_bf16.h>

#define N_TOK 4096
#define D_IN  512
#define D_HID 256
#define N_OUT 40

typedef _Float16 half8 __attribute__((ext_vector_type(8)));
typedef _Float16 half4 __attribute__((ext_vector_type(4)));
typedef float    f32x4 __attribute__((ext_vector_type(4)));

// async 16B/lane global->LDS DMA; lds dst is wave-uniform base (+lane*16 implicit)
__device__ __forceinline__ void async_copy16(const _Float16* g, _Float16* l) {
  __builtin_amdgcn_global_load_lds(
      (const __attribute__((address_space(1))) unsigned int*)(g),
      (__attribute__((address_space(3))) unsigned int*)(l), 16, 0, 0);
}

// ---------------------------------------------------------------------------
// prep: h -> fp16; W transposes via LDS 64x64 tiles (coalesced both sides)
// grid: 1024 (h) + 192 (Wqkv tiles) + 64 (Wo tiles) + 24 (Wp) = 1304
// ---------------------------------------------------------------------------
__device__ __forceinline__ void transpose_tile(const float* __restrict__ src, int in_ncols,
                                               _Float16* __restrict__ dst, int out_ncols,
                                               int i0, int d0, float* lds /* 64*65 */)
{
  int tid = threadIdx.x;
  int l15 = tid & 15, l4 = tid >> 4;
#pragma unroll
  for (int p = 0; p < 4; p++) {
    int ii = p * 16 + l4;
    float4 x = *(const float4*)(src + (size_t)(i0 + ii) * in_ncols + d0 + l15 * 4);
    lds[(l15 * 4 + 0) * 65 + ii] = x.x;
    lds[(l15 * 4 + 1) * 65 + ii] = x.y;
    lds[(l15 * 4 + 2) * 65 + ii] = x.z;
    lds[(l15 * 4 + 3) * 65 + ii] = x.w;
  }
  __syncthreads();
  int dd = tid >> 2, chunk = tid & 3;
  half8 o0, o1;
#pragma unroll
  for (int j = 0; j < 8; j++) o0[j] = (_Float16)lds[dd * 65 + chunk * 16 + j];
#pragma unroll
  for (int j = 0; j < 8; j++) o1[j] = (_Float16)lds[dd * 65 + chunk * 16 + 8 + j];
  *(half8*)(dst + (size_t)(d0 + dd) * out_ncols + i0 + chunk * 16) = o0;
  *(half8*)(dst + (size_t)(d0 + dd) * out_ncols + i0 + chunk * 16 + 8) = o1;
}

__global__ void prep_kernel(const float* __restrict__ h, const float* __restrict__ Wq,
                            const float* __restrict__ Wk, const float* __restrict__ Wv,
                            const float* __restrict__ Wo, const float* __restrict__ Wp,
                            _Float16* __restrict__ h16, _Float16* __restrict__ Wqt,
                            _Float16* __restrict__ Wkt, _Float16* __restrict__ Wvt,
                            _Float16* __restrict__ Wot, _Float16* __restrict__ Wpt)
{
  __shared__ float lds[64 * 65];
  int b = blockIdx.x, tid = threadIdx.x;
  if (b < 1024) {                              // h -> h16 (4096x512)
    int base = b * 2048 + tid * 8;
    float4 x0 = *(const float4*)(h + base);
    float4 x1 = *(const float4*)(h + base + 4);
    half8 o;
    o[0]=(_Float16)x0.x; o[1]=(_Float16)x0.y; o[2]=(_Float16)x0.z; o[3]=(_Float16)x0.w;
    o[4]=(_Float16)x1.x; o[5]=(_Float16)x1.y; o[6]=(_Float16)x1.z; o[7]=(_Float16)x1.w;
    *(half8*)(h16 + base) = o;
  } else if (b < 1216) {                       // Wq/Wk/Wv transpose, 64x64 tiles
    int t = b - 1024;                          // 0..191
    int mat = t >> 5;                          // 0..5
    int m = mat >> 1, head = mat & 1;
    const float* W = (m==0 ? Wq : (m==1 ? Wk : Wv)) + head * (D_IN * D_HID);
    _Float16* Wt   = (m==0 ? Wqt : (m==1 ? Wkt : Wvt)) + head * (D_IN * D_HID);
    int tt = t & 31;
    int i0 = (tt >> 2) * 64, d0 = (tt & 3) * 64;
    transpose_tile(W, D_HID, Wt, D_IN, i0, d0, lds);
  } else if (b < 1280) {                       // Wo transpose (512x512)
    int t = b - 1216;                          // 0..63
    int i0 = (t >> 3) * 64, d0 = (t & 7) * 64;
    transpose_tile(Wo, D_IN, Wot, D_IN, i0, d0, lds);
  } else {                                     // Wp transpose+pad to [48][512]
    int blk = b - 1280;                        // 0..23
    int idx = blk * 1024 + tid * 4;
    int j = idx >> 9, i = idx & 511;
    half4 o;
#pragma unroll
    for (int u = 0; u < 4; u++)
      o[u] = (j < N_OUT) ? (_Float16)Wp[(i + u) * N_OUT + j] : (_Float16)0.f;
    *(half4*)(Wpt + j * D_IN + i) = o;
  }
}

// ---------------------------------------------------------------------------
// proj: unified m97-style 128x128-tile GEMM, BK=64, LDS-staged A and B.
// Blocks 0..255: Q/K = h16 @ [Wqt;Wkt]. Blocks 256..383: VT directly.
// xor-swizzled 16B chunks; 2-barrier K-loop (m97 structure).
// ---------------------------------------------------------------------------
__global__ __launch_bounds__(256, 2) void proj_kernel(
    const _Float16* __restrict__ h16, const _Float16* __restrict__ W6 /*Wqt base*/,
    const _Float16* __restrict__ Wvt,
    const float* __restrict__ bq, const float* __restrict__ bk,
    const float* __restrict__ bv,
    _Float16* __restrict__ Q16, _Float16* __restrict__ K16,
    _Float16* __restrict__ VT16)
{
  __shared__ __align__(16) _Float16 Atile[128 * 64];   // 16 KB
  __shared__ __align__(16) _Float16 Btile[128 * 64];   // 16 KB

  int b = blockIdx.x;
  int tid = threadIdx.x, w = tid >> 6, lane = tid & 63, quad = lane >> 4, cL = lane & 15;
  int wr = w >> 1, wc = w & 1;

  const _Float16 *Asrc, *Bsrc;
  int isV;
  int m0 = 0, n0 = 0, head = 0, mh = 0;
  if (b < 256) {
    isV = 0;
    m0 = (b >> 3) * 128;
    int ct = b & 7;
    mh = ct >> 1;                       // 0,1: Q heads; 2,3: K heads
    n0 = (ct & 1) * 128;
    Asrc = h16 + (size_t)m0 * D_IN;
    Bsrc = W6 + (size_t)(ct * 128) * D_IN;
  } else {
    isV = 1;
    int t = b - 256;
    head = t >> 6;
    int tt = t & 63;
    m0 = (tt >> 5) * 128;               // d-half base
    n0 = (tt & 31) * 128;               // token base
    Asrc = Wvt + (size_t)head * (D_HID * D_IN) + (size_t)m0 * D_IN;
    Bsrc = h16 + (size_t)n0 * D_IN;
  }

  const f32x4 z4 = {0.f, 0.f, 0.f, 0.f};
  f32x4 acc[4][4];
#pragma unroll
  for (int i = 0; i < 4; i++)
#pragma unroll
    for (int j = 0; j < 4; j++) acc[i][j] = z4;

  int r8 = lane >> 3, chs = (lane & 7) ^ r8;   // staging row-in-8 / swizzled chunk

  for (int kc = 0; kc < 8; kc++) {
    __syncthreads();
#pragma unroll
    for (int g = 0; g < 4; g++) {
      int row = (w * 4 + g) * 8 + r8;
      async_copy16(Asrc + (size_t)row * D_IN + kc * 64 + chs * 8, Atile + (w * 4 + g) * 512);
      async_copy16(Bsrc + (size_t)row * D_IN + kc * 64 + chs * 8, Btile + (w * 4 + g) * 512);
    }
    __syncthreads();   // drain DMA
#pragma unroll
    for (int kk = 0; kk < 2; kk++) {
      int ch = ((kk * 4 + quad) ^ (cL & 7)) * 8;
      half8 a[4], bf[4];
#pragma unroll
      for (int mt = 0; mt < 4; mt++)
        a[mt] = *(const half8*)(Atile + (wr * 64 + mt * 16 + cL) * 64 + ch);
#pragma unroll
      for (int nt = 0; nt < 4; nt++)
        bf[nt] = *(const half8*)(Btile + (wc * 64 + nt * 16 + cL) * 64 + ch);
#pragma unroll
      for (int mt = 0; mt < 4; mt++)
#pragma unroll
        for (int nt = 0; nt < 4; nt++)
          acc[mt][nt] = __builtin_amdgcn_mfma_f32_16x16x32_f16(a[mt], bf[nt], acc[mt][nt], 0, 0, 0);
    }
  }

  if (!isV) {
    _Float16* Out = (mh < 2 ? Q16 + (size_t)mh * (N_TOK * D_HID)
                            : K16 + (size_t)(mh - 2) * (N_TOK * D_HID));
    const float* bias = (mh < 2 ? bq + mh * D_HID : bk + (mh - 2) * D_HID);
#pragma unroll
    for (int mt = 0; mt < 4; mt++) {
      int row = m0 + wr * 64 + mt * 16 + quad * 4;
#pragma unroll
      for (int nt = 0; nt < 4; nt++) {
        int colg = n0 + wc * 64 + nt * 16 + cL;
        float bb = bias[colg];
#pragma unroll
        for (int reg = 0; reg < 4; reg++)
          Out[(size_t)(row + reg) * D_HID + colg] = (_Float16)(acc[mt][nt][reg] + bb);
      }
    }
  } else {
    _Float16* VTh = VT16 + (size_t)head * (N_TOK * D_HID);
    const float* bvh = bv + head * D_HID;
#pragma unroll
    for (int mt = 0; mt < 4; mt++) {
      int d0r = m0 + wr * 64 + mt * 16 + quad * 4;
      float bvv[4];
#pragma unroll
      for (int reg = 0; reg < 4; reg++) bvv[reg] = bvh[d0r + reg];
#pragma unroll
      for (int nt = 0; nt < 4; nt++) {
        int tok = n0 + wc * 64 + nt * 16 + cL;
#pragma unroll
        for (int reg = 0; reg < 4; reg++)
          VTh[(size_t)(d0r + reg) * N_TOK + tok] = (_Float16)(acc[mt][nt][reg] + bvv[reg]);
      }
    }
  }
}

// ---------------------------------------------------------------------------
// attn: flash attention, FAT-WAVE version. 256 threads / 4 waves per block,
// each wave owns 32 q-rows (2 q-subtiles of 16). grid 256 = 1 block/CU.
// Every K/V fragment read from LDS feeds TWO MFMAs (one per q-subtile) ->
// LDS read instructions per CU-iter halve vs the 8-thin-wave version.
// K and V double-buffered (2x32 + 2x32 + 18KB Pbuf = 146KB LDS); tile it+1's
// DMA issues at iteration top, ONE barrier per iteration. setprio around the
// MFMA clusters. adj prefetched one iteration ahead in registers.
// grid 256 = 2 heads x 4 KV-splits x 32 rowgroups; b%8=(head,gs) for XCD/L2.
// ---------------------------------------------------------------------------
__global__ __launch_bounds__(256, 1) void attn_kernel(
    const float* __restrict__ adj, const _Float16* __restrict__ Q16,
    const _Float16* __restrict__ K16, const _Float16* __restrict__ VT16,
    _Float16* __restrict__ Opart, float* __restrict__ Mpart, float* __restrict__ Lpart)
{
  __shared__ __align__(16) _Float16 Kt[2][64 * 256];    // 2 x 32 KB  [key][d]
  __shared__ __align__(16) _Float16 Vt[2][256 * 64];    // 2 x 32 KB  [d][tok]
  __shared__ __align__(16) _Float16 Pbuf[4 * 32 * 72];  // 18 KB

  int b = blockIdx.x;
  int head = (b >> 2) & 1;
  int gs = b & 3;
  int q0 = (b >> 3) * 128;

  int tid = threadIdx.x;
  int w = tid >> 6, lane = tid & 63, quad = lane >> 4, cL = lane & 15;

  const _Float16* Qh = Q16 + head * (N_TOK * D_HID);
  const _Float16* Kh = K16 + head * (N_TOK * D_HID);
  const _Float16* Vh = VT16 + head * (N_TOK * D_HID);
  const float* adjh = adj + (size_t)head * N_TOK * N_TOK;

  int qrow = q0 + w * 32;                 // wave owns rows qrow..qrow+31
  int nstart = gs * 1024;
  const f32x4 z4 = {0.f, 0.f, 0.f, 0.f};

  half8 qf[2][8];
#pragma unroll
  for (int qt = 0; qt < 2; qt++)
#pragma unroll
    for (int t = 0; t < 8; t++)
      qf[qt][t] = *(const half8*)(Qh + (qrow + qt * 16 + cL) * D_HID + t * 32 + quad * 8);

  f32x4 acc[2][16];
#pragma unroll
  for (int qt = 0; qt < 2; qt++)
#pragma unroll
    for (int i = 0; i < 16; i++) acc[qt][i] = z4;
  float m_i[2][4] = {{-1e30f, -1e30f, -1e30f, -1e30f}, {-1e30f, -1e30f, -1e30f, -1e30f}};
  float l_i[2][4] = {{0.f, 0.f, 0.f, 0.f}, {0.f, 0.f, 0.f, 0.f}};

  _Float16* pb = Pbuf + w * (32 * 72);

  const float* adjR[2][4];
#pragma unroll
  for (int qt = 0; qt < 2; qt++)
#pragma unroll
    for (int reg = 0; reg < 4; reg++)
      adjR[qt][reg] = adjh + (size_t)(qrow + qt * 16 + quad * 4 + reg) * N_TOK + nstart + cL;

  int l5 = lane >> 5, l31 = lane & 31;   // K staging: 2 rows (512B) per copy
  int l3 = lane >> 3, l7 = lane & 7;     // V staging: 8 rows (128B) per copy

  // stage K tile (64 keys x 256 d); xor-swizzled 16B chunks in 512B rows.
  // 32 groups of 2 rows; wave w handles groups w*8..w*8+7.
  auto stageK = [&](int it, _Float16* dst) {
    int n0 = nstart + it * 64;
#pragma unroll
    for (int i = 0; i < 8; i++) {
      int g = w * 8 + i;
      int rK = 2 * g + l5;
      int cK = l31 ^ (rK & 7);
      async_copy16(Kh + (size_t)(n0 + rK) * D_HID + cK * 8, dst + g * 512);
    }
  };
  // stage V tile (256 d x 64 tok); xor-swizzled 16B chunks in 128B rows.
  auto stageV = [&](int it, _Float16* dst) {
    int n0 = nstart + it * 64;
#pragma unroll
    for (int i = 0; i < 8; i++) {
      int g = w * 8 + i;
      int rV = g * 8 + l3;
      int cV = l7 ^ (rV & 7);
      async_copy16(Vh + (size_t)rV * N_TOK + n0 + cV * 8, dst + g * 512);
    }
  };
  auto loadAdj = [&](int it, float (&av)[2][4][4]) {
#pragma unroll
    for (int qt = 0; qt < 2; qt++)
#pragma unroll
      for (int reg = 0; reg < 4; reg++)
#pragma unroll
        for (int ct = 0; ct < 4; ct++)
          av[qt][reg][ct] = __builtin_nontemporal_load(adjR[qt][reg] + it * 64 + ct * 16);
  };

  auto body = [&](int it, const _Float16* KC, const _Float16* VC,
                  _Float16* KN, _Float16* VN,
                  float (&avC)[2][4][4], float (&avN)[2][4][4]) {
    // prefetch tile it+1 (K+V DMA + adj) before any compute on tile it
    if (it + 1 < 16) {
      stageK(it + 1, KN);
      stageV(it + 1, VN);
      loadAdj(it + 1, avN);
    }

    // QK^T : S[32q][64k]; each kf feeds both q-subtiles
    f32x4 s[2][4];
#pragma unroll
    for (int qt = 0; qt < 2; qt++)
#pragma unroll
      for (int ct = 0; ct < 4; ct++) s[qt][ct] = z4;
    __builtin_amdgcn_s_setprio(1);
#pragma unroll
    for (int t = 0; t < 8; t++) {
#pragma unroll
      for (int ct = 0; ct < 4; ct++) {
        int rK = ct * 16 + cL;
        int ck = (t * 4 + quad) ^ (rK & 7);
        half8 kf = *(const half8*)(KC + rK * 256 + ck * 8);
        s[0][ct] = __builtin_amdgcn_mfma_f32_16x16x32_f16(qf[0][t], kf, s[0][ct], 0, 0, 0);
        s[1][ct] = __builtin_amdgcn_mfma_f32_16x16x32_f16(qf[1][t], kf, s[1][ct], 0, 0, 0);
      }
    }
    __builtin_amdgcn_s_setprio(0);

    // mask + online softmax (rows = qt*16 + quad*4+reg, cols = ct*16+cL)
    float alpha[2][4];
#pragma unroll
    for (int qt = 0; qt < 2; qt++) {
#pragma unroll
      for (int reg = 0; reg < 4; reg++) {
#pragma unroll
        for (int ct = 0; ct < 4; ct++) s[qt][ct][reg] *= avC[qt][reg][ct];
        float mx = fmaxf(fmaxf(s[qt][0][reg], s[qt][1][reg]), fmaxf(s[qt][2][reg], s[qt][3][reg]));
#pragma unroll
        for (int msk = 1; msk < 16; msk <<= 1) mx = fmaxf(mx, __shfl_xor(mx, msk, 16));
        float mnew = fmaxf(m_i[qt][reg], mx);
        alpha[qt][reg] = __expf(m_i[qt][reg] - mnew);
        m_i[qt][reg] = mnew;
        float rs = 0.f;
#pragma unroll
        for (int ct = 0; ct < 4; ct++) {
          float p = __expf(s[qt][ct][reg] - mnew);
          s[qt][ct][reg] = p;
          rs += p;
        }
#pragma unroll
        for (int msk = 1; msk < 16; msk <<= 1) rs += __shfl_xor(rs, msk, 16);
        l_i[qt][reg] = l_i[qt][reg] * alpha[qt][reg] + rs;
      }
    }

    // P -> LDS (per-wave buffer, same-wave lgkm ordering only)
#pragma unroll
    for (int qt = 0; qt < 2; qt++)
#pragma unroll
      for (int reg = 0; reg < 4; reg++)
#pragma unroll
        for (int ct = 0; ct < 4; ct++)
          pb[(qt * 16 + quad * 4 + reg) * 72 + ct * 16 + cL] = (_Float16)s[qt][ct][reg];

    // rescale acc only if any row's max grew (alpha==1 exactly when unchanged)
#pragma unroll
    for (int qt = 0; qt < 2; qt++) {
      if (__any(alpha[qt][0] * alpha[qt][1] * alpha[qt][2] * alpha[qt][3] != 1.0f)) {
#pragma unroll
        for (int dt = 0; dt < 16; dt++)
#pragma unroll
          for (int reg = 0; reg < 4; reg++)
            acc[qt][dt][reg] *= alpha[qt][reg];
      }
    }

    // PV : acc[q][d] += P[q][k] * V[d][k]; each v-fragment feeds both q-subtiles
    half8 pf0[2], pf1[2];
#pragma unroll
    for (int qt = 0; qt < 2; qt++) {
      pf0[qt] = *(const half8*)(pb + (qt * 16 + cL) * 72 + quad * 8);
      pf1[qt] = *(const half8*)(pb + (qt * 16 + cL) * 72 + 32 + quad * 8);
    }
    __builtin_amdgcn_s_setprio(1);
#pragma unroll
    for (int dt = 0; dt < 16; dt++) {
      int rV = dt * 16 + cL;
      int c0 = (quad) ^ (rV & 7);
      int c1 = (4 + quad) ^ (rV & 7);
      half8 v0 = *(const half8*)(VC + rV * 64 + c0 * 8);
      half8 v1 = *(const half8*)(VC + rV * 64 + c1 * 8);
      acc[0][dt] = __builtin_amdgcn_mfma_f32_16x16x32_f16(pf0[0], v0, acc[0][dt], 0, 0, 0);
      acc[0][dt] = __builtin_amdgcn_mfma_f32_16x16x32_f16(pf1[0], v1, acc[0][dt], 0, 0, 0);
      acc[1][dt] = __builtin_amdgcn_mfma_f32_16x16x32_f16(pf0[1], v0, acc[1][dt], 0, 0, 0);
      acc[1][dt] = __builtin_amdgcn_mfma_f32_16x16x32_f16(pf1[1], v1, acc[1][dt], 0, 0, 0);
    }
    __builtin_amdgcn_s_setprio(0);

    // single barrier: drains prefetch DMA (vmcnt 0) + retires KC/VC reads
    // before the next iteration's stage overwrites them.
    __syncthreads();
  };

  // prologue: tile 0 into buffer 0
  stageK(0, Kt[0]);
  stageV(0, Vt[0]);
  float avA[2][4][4], avB[2][4][4];
  loadAdj(0, avA);
  __syncthreads();

  for (int itp = 0; itp < 8; ++itp) {
    body(2 * itp,     Kt[0], Vt[0], Kt[1], Vt[1], avA, avB);
    body(2 * itp + 1, Kt[1], Vt[1], Kt[0], Vt[0], avB, avA);
  }

#pragma unroll
  for (int qt = 0; qt < 2; qt++) {
    int prow = (head * 4 + gs) * N_TOK + qrow + qt * 16 + quad * 4;
#pragma unroll
    for (int reg = 0; reg < 4; reg++) {
      int row = prow + reg;
#pragma unroll
      for (int dt = 0; dt < 16; dt++)
        Opart[(size_t)row * D_HID + dt * 16 + cL] = (_Float16)acc[qt][dt][reg];
      if (cL == 0) { Mpart[row] = m_i[qt][reg]; Lpart[row] = l_i[qt][reg]; }
    }
  }
}

// ---------------------------------------------------------------------------
// final (fused with merge): per 16-row block, combine the 4 KV splits on the
// fly from Opart/Mpart/Lpart into the af[] A-fragments, then z = X@Wo + bo
// -> LayerNorm -> softmax(M@Wp + bp) -> out [4096][40]. grid 256 x 256 thr.
// ---------------------------------------------------------------------------
__global__ __launch_bounds__(256, 1) void final_kernel(
    const _Float16* __restrict__ Opart, const float* __restrict__ Mpart,
    const float* __restrict__ Lpart, const _Float16* __restrict__ Wot,
    const _Float16* __restrict__ Wpt, const float* __restrict__ bo,
    const float* __restrict__ gamma, const float* __restrict__ beta,
    const float* __restrict__ bp, float* __restrict__ out)
{
  __shared__ __align__(16) _Float16 Btile[512 * 64];   // 64 KB
  __shared__ __align__(16) _Float16 Mlds[16 * 520];
  __shared__ float outs[16 * 48];
  __shared__ float lnsum[4][16], lnsq[4][16];
  __shared__ float smx[16], srl[16];

  int rowbase = blockIdx.x * 16;
  int tid = threadIdx.x, w = tid >> 6, lane = tid & 63, quad = lane >> 4, cL = lane & 15;
  const f32x4 z4 = {0.f, 0.f, 0.f, 0.f};
  int row = rowbase + cL;

  // ---- merge phase: per-head split weights f[s]*rl for this thread's row
  float fr[2][4];
#pragma unroll
  for (int hd = 0; hd < 2; hd++) {
    float m[4], l[4];
    float mm = -1e30f;
#pragma unroll
    for (int s = 0; s < 4; s++) {
      int idx = (hd * 4 + s) * N_TOK + row;
      m[s] = Mpart[idx];
      l[s] = Lpart[idx];
      mm = fmaxf(mm, m[s]);
    }
    float f_[4], L = 0.f;
#pragma unroll
    for (int s = 0; s < 4; s++) { f_[s] = __expf(m[s] - mm); L += f_[s] * l[s]; }
    float rl = 1.0f / L;
#pragma unroll
    for (int s = 0; s < 4; s++) fr[hd][s] = f_[s] * rl;
  }

  // ---- A-fragments: af[t] = X[row][t*32 + quad*8 .. +8] merged from 4 splits
  half8 af[16];
#pragma unroll
  for (int t = 0; t < 16; t++) {
    int hd = t >> 3;                       // col = hd*256 + dg
    int dg = (t & 7) * 32 + quad * 8;
    float o[8] = {0.f, 0.f, 0.f, 0.f, 0.f, 0.f, 0.f, 0.f};
#pragma unroll
    for (int s = 0; s < 4; s++) {
      half8 os = *(const half8*)(Opart + (size_t)((hd * 4 + s) * N_TOK + row) * D_HID + dg);
#pragma unroll
      for (int u = 0; u < 8; u++) o[u] += (float)os[u] * fr[hd][s];
    }
#pragma unroll
    for (int u = 0; u < 8; u++) af[t][u] = (_Float16)o[u];
  }

  f32x4 acc[8];
#pragma unroll
  for (int i = 0; i < 8; i++) acc[i] = z4;

  int r8 = lane >> 3, chs = (lane & 7) ^ r8;

  for (int kc = 0; kc < 8; kc++) {
    __syncthreads();
#pragma unroll
    for (int g = 0; g < 16; g++) {
      int grow = (w * 16 + g) * 8 + r8;
      async_copy16(Wot + (size_t)grow * D_IN + kc * 64 + chs * 8, Btile + (w * 16 + g) * 512);
    }
    __syncthreads();
#pragma unroll
    for (int kk = 0; kk < 2; kk++) {
      int ch = ((kk * 4 + quad) ^ (cL & 7)) * 8;
      half8 a = af[kc * 2 + kk];
      half8 bf[8];
#pragma unroll
      for (int nt = 0; nt < 8; nt++)
        bf[nt] = *(const half8*)(Btile + (w * 128 + nt * 16 + cL) * 64 + ch);
#pragma unroll
      for (int nt = 0; nt < 8; nt++)
        acc[nt] = __builtin_amdgcn_mfma_f32_16x16x32_f16(a, bf[nt], acc[nt], 0, 0, 0);
    }
  }

  float sum[4] = {0, 0, 0, 0}, sq[4] = {0, 0, 0, 0};
#pragma unroll
  for (int nt = 0; nt < 8; nt++) {
    int col = w * 128 + nt * 16 + cL;
    float bb = bo[col];
#pragma unroll
    for (int reg = 0; reg < 4; reg++) {
      float z = acc[nt][reg] + bb;
      acc[nt][reg] = z;
      sum[reg] += z;
      sq[reg] += z * z;
    }
  }
#pragma unroll
  for (int reg = 0; reg < 4; reg++) {
#pragma unroll
    for (int msk = 1; msk < 16; msk <<= 1) {
      sum[reg] += __shfl_xor(sum[reg], msk, 16);
      sq[reg]  += __shfl_xor(sq[reg], msk, 16);
    }
  }
  if (cL == 0) {
#pragma unroll
    for (int reg = 0; reg < 4; reg++) {
      lnsum[w][quad * 4 + reg] = sum[reg];
      lnsq[w][quad * 4 + reg]  = sq[reg];
    }
  }
  __syncthreads();
  float mean[4], rstd[4];
#pragma unroll
  for (int reg = 0; reg < 4; reg++) {
    int r = quad * 4 + reg;
    float s  = lnsum[0][r] + lnsum[1][r] + lnsum[2][r] + lnsum[3][r];
    float s2 = lnsq[0][r]  + lnsq[1][r]  + lnsq[2][r]  + lnsq[3][r];
    float mu = s * (1.0f / 512.0f);
    float var = s2 * (1.0f / 512.0f) - mu * mu;
    mean[reg] = mu;
    rstd[reg] = rsqrtf(var + 1e-5f);
  }
#pragma unroll
  for (int nt = 0; nt < 8; nt++) {
    int col = w * 128 + nt * 16 + cL;
    float g = gamma[col], be = beta[col];
#pragma unroll
    for (int reg = 0; reg < 4; reg++) {
      float mval = (acc[nt][reg] - mean[reg]) * rstd[reg] * g + be;
      Mlds[(quad * 4 + reg) * 520 + col] = (_Float16)mval;
    }
  }
  __syncthreads();
  if (w < 3) {
    int jt = w;
    f32x4 a2 = z4;
#pragma unroll
    for (int t = 0; t < 16; t++) {
      half8 am = *(const half8*)(Mlds + cL * 520 + t * 32 + quad * 8);
      half8 bm = *(const half8*)(Wpt + (jt * 16 + cL) * D_IN + t * 32 + quad * 8);
      a2 = __builtin_amdgcn_mfma_f32_16x16x32_f16(am, bm, a2, 0, 0, 0);
    }
    int col = jt * 16 + cL;
    float bpv = (col < N_OUT) ? bp[col] : 0.0f;
#pragma unroll
    for (int reg = 0; reg < 4; reg++)
      outs[(quad * 4 + reg) * 48 + col] = a2[reg] + bpv;
  }
  __syncthreads();
  if (tid < 16) {
    int r = tid;
    float mx = -1e30f;
    for (int j = 0; j < N_OUT; j++) mx = fmaxf(mx, outs[r * 48 + j]);
    float ssum = 0.f;
    for (int j = 0; j < N_OUT; j++) ssum += __expf(outs[r * 48 + j] - mx);
    smx[r] = mx;
    srl[r] = 1.0f / ssum;
  }
  __syncthreads();
#pragma unroll
  for (int i = 0; i < 3; i++) {
    int lin = tid + 256 * i;
    if (lin < 16 * N_OUT) {
      int r = lin / N_OUT, col = lin % N_OUT;
      out[(size_t)(rowbase + r) * N_OUT + col] =
          __expf(outs[r * 48 + col] - smx[r]) * srl[r];
    }
  }
}

// ---------------------------------------------------------------------------
// Workspace layout (bytes, 256-aligned). Opart overlays buffers dead by attn
// time (h16, Wqt/Wkt/Wvt). V16 eliminated (VT computed directly in proj).
// Xf eliminated (merge fused into final).
// ---------------------------------------------------------------------------
#define OFF_WOT   0u
#define OFF_WPT   524288u
#define OFF_Q16   573440u
#define OFF_K16   4767744u
#define OFF_VT16  8962048u
#define OFF_MP    13156352u
#define OFF_LP    13287424u
#define OFF_OP    17612800u
// overlay (dead before attn):
#define OFF_H16   17612800u
#define OFF_WQT   21807104u
#define OFF_WKT   22331392u
#define OFF_WVT   22855680u

extern "C" void kernel_launch(void* const* d_in, const int* in_sizes, int n_in,
                              void* d_out, int out_size, void* d_ws, size_t ws_size,
                              hipStream_t stream)
{
  const float* adj   = (const float*)d_in[0];
  const float* h     = (const float*)d_in[1];
  const float* Wq    = (const float*)d_in[2];
  const float* bq    = (const float*)d_in[3];
  const float* Wk    = (const float*)d_in[4];
  const float* bk    = (const float*)d_in[5];
  const float* Wv    = (const float*)d_in[6];
  const float* bv    = (const float*)d_in[7];
  const float* Wo    = (const float*)d_in[8];
  const float* bo    = (const float*)d_in[9];
  const float* gamma = (const float*)d_in[10];
  const float* beta  = (const float*)d_in[11];
  const float* Wp    = (const float*)d_in[12];
  const float* bp    = (const float*)d_in[13];
  float* out = (float*)d_out;
  char* ws = (char*)d_ws;

  _Float16* h16   = (_Float16*)(ws + OFF_H16);
  _Float16* Wqt   = (_Float16*)(ws + OFF_WQT);
  _Float16* Wkt   = (_Float16*)(ws + OFF_WKT);
  _Float16* Wvt   = (_Float16*)(ws + OFF_WVT);
  _Float16* Wot   = (_Float16*)(ws + OFF_WOT);
  _Float16* Wpt   = (_Float16*)(ws + OFF_WPT);
  _Float16* Q16   = (_Float16*)(ws + OFF_Q16);
  _Float16* K16   = (_Float16*)(ws + OFF_K16);
  _Float16* VT16  = (_Float16*)(ws + OFF_VT16);
  _Float16* Opart = (_Float16*)(ws + OFF_OP);
  float*    Mpart = (float*)(ws + OFF_MP);
  float*    Lpart = (float*)(ws + OFF_LP);

  prep_kernel<<<1304, 256, 0, stream>>>(h, Wq, Wk, Wv, Wo, Wp,
                                        h16, Wqt, Wkt, Wvt, Wot, Wpt);
  proj_kernel<<<384, 256, 0, stream>>>(h16, Wqt, Wvt, bq, bk, bv,
                                       Q16, K16, VT16);
  attn_kernel<<<256, 256, 0, stream>>>(adj, Q16, K16, VT16, Opart, Mpart, Lpart);
  final_kernel<<<256, 256, 0, stream>>>(Opart, Mpart, Lpart, Wot, Wpt,
                                        bo, gamma, beta, bp, out);
}

// Round 6
// 300.331 us; speedup vs baseline: 5.0587x; 5.0587x over previous
//
#include <hip/hip_runtime.h>
#include <hip/hip_bf16.h>

#define N_TOK 4096
#define D_IN  512
#define D_HID 256
#define N_OUT 40

typedef _Float16 half8 __attribute__((ext_vector_type(8)));
typedef _Float16 half4 __attribute__((ext_vector_type(4)));
typedef float    f32x4 __attribute__((ext_vector_type(4)));

// async 16B/lane global->LDS DMA; lds dst is wave-uniform base (+lane*16 implicit)
__device__ __forceinline__ void async_copy16(const _Float16* g, _Float16* l) {
  __builtin_amdgcn_global_load_lds(
      (const __attribute__((address_space(1))) unsigned int*)(g),
      (__attribute__((address_space(3))) unsigned int*)(l), 16, 0, 0);
}

// ---------------------------------------------------------------------------
// prep: h -> fp16; W transposes via LDS 64x64 tiles (coalesced both sides)
// grid: 1024 (h) + 192 (Wqkv tiles) + 64 (Wo tiles) + 24 (Wp) = 1304
// ---------------------------------------------------------------------------
__device__ __forceinline__ void transpose_tile(const float* __restrict__ src, int in_ncols,
                                               _Float16* __restrict__ dst, int out_ncols,
                                               int i0, int d0, float* lds /* 64*65 */)
{
  int tid = threadIdx.x;
  int l15 = tid & 15, l4 = tid >> 4;
#pragma unroll
  for (int p = 0; p < 4; p++) {
    int ii = p * 16 + l4;
    float4 x = *(const float4*)(src + (size_t)(i0 + ii) * in_ncols + d0 + l15 * 4);
    lds[(l15 * 4 + 0) * 65 + ii] = x.x;
    lds[(l15 * 4 + 1) * 65 + ii] = x.y;
    lds[(l15 * 4 + 2) * 65 + ii] = x.z;
    lds[(l15 * 4 + 3) * 65 + ii] = x.w;
  }
  __syncthreads();
  int dd = tid >> 2, chunk = tid & 3;
  half8 o0, o1;
#pragma unroll
  for (int j = 0; j < 8; j++) o0[j] = (_Float16)lds[dd * 65 + chunk * 16 + j];
#pragma unroll
  for (int j = 0; j < 8; j++) o1[j] = (_Float16)lds[dd * 65 + chunk * 16 + 8 + j];
  *(half8*)(dst + (size_t)(d0 + dd) * out_ncols + i0 + chunk * 16) = o0;
  *(half8*)(dst + (size_t)(d0 + dd) * out_ncols + i0 + chunk * 16 + 8) = o1;
}

__global__ void prep_kernel(const float* __restrict__ h, const float* __restrict__ Wq,
                            const float* __restrict__ Wk, const float* __restrict__ Wv,
                            const float* __restrict__ Wo, const float* __restrict__ Wp,
                            _Float16* __restrict__ h16, _Float16* __restrict__ Wqt,
                            _Float16* __restrict__ Wkt, _Float16* __restrict__ Wvt,
                            _Float16* __restrict__ Wot, _Float16* __restrict__ Wpt)
{
  __shared__ float lds[64 * 65];
  int b = blockIdx.x, tid = threadIdx.x;
  if (b < 1024) {                              // h -> h16 (4096x512)
    int base = b * 2048 + tid * 8;
    float4 x0 = *(const float4*)(h + base);
    float4 x1 = *(const float4*)(h + base + 4);
    half8 o;
    o[0]=(_Float16)x0.x; o[1]=(_Float16)x0.y; o[2]=(_Float16)x0.z; o[3]=(_Float16)x0.w;
    o[4]=(_Float16)x1.x; o[5]=(_Float16)x1.y; o[6]=(_Float16)x1.z; o[7]=(_Float16)x1.w;
    *(half8*)(h16 + base) = o;
  } else if (b < 1216) {                       // Wq/Wk/Wv transpose, 64x64 tiles
    int t = b - 1024;                          // 0..191
    int mat = t >> 5;                          // 0..5
    int m = mat >> 1, head = mat & 1;
    const float* W = (m==0 ? Wq : (m==1 ? Wk : Wv)) + head * (D_IN * D_HID);
    _Float16* Wt   = (m==0 ? Wqt : (m==1 ? Wkt : Wvt)) + head * (D_IN * D_HID);
    int tt = t & 31;
    int i0 = (tt >> 2) * 64, d0 = (tt & 3) * 64;
    transpose_tile(W, D_HID, Wt, D_IN, i0, d0, lds);
  } else if (b < 1280) {                       // Wo transpose (512x512)
    int t = b - 1216;                          // 0..63
    int i0 = (t >> 3) * 64, d0 = (t & 7) * 64;
    transpose_tile(Wo, D_IN, Wot, D_IN, i0, d0, lds);
  } else {                                     // Wp transpose+pad to [48][512]
    int blk = b - 1280;                        // 0..23
    int idx = blk * 1024 + tid * 4;
    int j = idx >> 9, i = idx & 511;
    half4 o;
#pragma unroll
    for (int u = 0; u < 4; u++)
      o[u] = (j < N_OUT) ? (_Float16)Wp[(i + u) * N_OUT + j] : (_Float16)0.f;
    *(half4*)(Wpt + j * D_IN + i) = o;
  }
}

// ---------------------------------------------------------------------------
// proj: unified 128x128-tile GEMM, BK=64, double-buffered LDS with a single
// barrier per kc (prefetch kc+1 while computing kc; end-of-iter barrier
// drains DMA that had a full compute phase to land). Ran correct in R1.
// Blocks 0..255: Q/K = h16 @ [Wqt;Wkt]. Blocks 256..383: VT directly.
// ---------------------------------------------------------------------------
__global__ __launch_bounds__(256, 2) void proj_kernel(
    const _Float16* __restrict__ h16, const _Float16* __restrict__ W6 /*Wqt base*/,
    const _Float16* __restrict__ Wvt,
    const float* __restrict__ bq, const float* __restrict__ bk,
    const float* __restrict__ bv,
    _Float16* __restrict__ Q16, _Float16* __restrict__ K16,
    _Float16* __restrict__ VT16)
{
  __shared__ __align__(16) _Float16 Atile[2][128 * 64];   // 2 x 16 KB
  __shared__ __align__(16) _Float16 Btile[2][128 * 64];   // 2 x 16 KB

  int b = blockIdx.x;
  int tid = threadIdx.x, w = tid >> 6, lane = tid & 63, quad = lane >> 4, cL = lane & 15;
  int wr = w >> 1, wc = w & 1;

  const _Float16 *Asrc, *Bsrc;
  int isV;
  int m0 = 0, n0 = 0, head = 0, mh = 0;
  if (b < 256) {
    isV = 0;
    m0 = (b >> 3) * 128;
    int ct = b & 7;
    mh = ct >> 1;                       // 0,1: Q heads; 2,3: K heads
    n0 = (ct & 1) * 128;
    Asrc = h16 + (size_t)m0 * D_IN;
    Bsrc = W6 + (size_t)(ct * 128) * D_IN;
  } else {
    isV = 1;
    int t = b - 256;
    head = t >> 6;
    int tt = t & 63;
    m0 = (tt >> 5) * 128;               // d-half base
    n0 = (tt & 31) * 128;               // token base
    Asrc = Wvt + (size_t)head * (D_HID * D_IN) + (size_t)m0 * D_IN;
    Bsrc = h16 + (size_t)n0 * D_IN;
  }

  const f32x4 z4 = {0.f, 0.f, 0.f, 0.f};
  f32x4 acc[4][4];
#pragma unroll
  for (int i = 0; i < 4; i++)
#pragma unroll
    for (int j = 0; j < 4; j++) acc[i][j] = z4;

  int r8 = lane >> 3, chs = (lane & 7) ^ r8;   // staging row-in-8 / swizzled chunk

  auto stage = [&](int kc, int pb) {
#pragma unroll
    for (int g = 0; g < 4; g++) {
      int row = (w * 4 + g) * 8 + r8;
      async_copy16(Asrc + (size_t)row * D_IN + kc * 64 + chs * 8, Atile[pb] + (w * 4 + g) * 512);
      async_copy16(Bsrc + (size_t)row * D_IN + kc * 64 + chs * 8, Btile[pb] + (w * 4 + g) * 512);
    }
  };

  stage(0, 0);
  __syncthreads();   // drain first tile

  for (int kc = 0; kc < 8; kc++) {
    int cur = kc & 1;
    if (kc + 1 < 8) stage(kc + 1, cur ^ 1);
#pragma unroll
    for (int kk = 0; kk < 2; kk++) {
      int ch = ((kk * 4 + quad) ^ (cL & 7)) * 8;
      half8 a[4], bf[4];
#pragma unroll
      for (int mt = 0; mt < 4; mt++)
        a[mt] = *(const half8*)(Atile[cur] + (wr * 64 + mt * 16 + cL) * 64 + ch);
#pragma unroll
      for (int nt = 0; nt < 4; nt++)
        bf[nt] = *(const half8*)(Btile[cur] + (wc * 64 + nt * 16 + cL) * 64 + ch);
#pragma unroll
      for (int mt = 0; mt < 4; mt++)
#pragma unroll
        for (int nt = 0; nt < 4; nt++)
          acc[mt][nt] = __builtin_amdgcn_mfma_f32_16x16x32_f16(a[mt], bf[nt], acc[mt][nt], 0, 0, 0);
    }
    __syncthreads();   // retire reads of [cur] + drain prefetch DMA into [cur^1]
  }

  if (!isV) {
    _Float16* Out = (mh < 2 ? Q16 + (size_t)mh * (N_TOK * D_HID)
                            : K16 + (size_t)(mh - 2) * (N_TOK * D_HID));
    const float* bias = (mh < 2 ? bq + mh * D_HID : bk + (mh - 2) * D_HID);
#pragma unroll
    for (int mt = 0; mt < 4; mt++) {
      int row = m0 + wr * 64 + mt * 16 + quad * 4;
#pragma unroll
      for (int nt = 0; nt < 4; nt++) {
        int colg = n0 + wc * 64 + nt * 16 + cL;
        float bb = bias[colg];
#pragma unroll
        for (int reg = 0; reg < 4; reg++)
          Out[(size_t)(row + reg) * D_HID + colg] = (_Float16)(acc[mt][nt][reg] + bb);
      }
    }
  } else {
    _Float16* VTh = VT16 + (size_t)head * (N_TOK * D_HID);
    const float* bvh = bv + head * D_HID;
#pragma unroll
    for (int mt = 0; mt < 4; mt++) {
      int d0r = m0 + wr * 64 + mt * 16 + quad * 4;
      float bvv[4];
#pragma unroll
      for (int reg = 0; reg < 4; reg++) bvv[reg] = bvh[d0r + reg];
#pragma unroll
      for (int nt = 0; nt < 4; nt++) {
        int tok = n0 + wc * 64 + nt * 16 + cL;
#pragma unroll
        for (int reg = 0; reg < 4; reg++)
          VTh[(size_t)(d0r + reg) * N_TOK + tok] = (_Float16)(acc[mt][nt][reg] + bvv[reg]);
      }
    }
  }
}

// ---------------------------------------------------------------------------
// attn: flash attention (EXACT R4 revert — proven 85us, VGPR 124).
// 512 threads / 8 waves per block, 128 q-rows/block, grid 256 = 1 block/CU.
// K and V double-buffered; tile it+1's DMA issues at iteration top, ONE
// barrier per iteration. setprio around the MFMA clusters. adj prefetched
// one iteration ahead in registers.
// grid 256 = 2 heads x 4 KV-splits x 32 rowgroups; b%8=(head,gs) for XCD/L2.
// ---------------------------------------------------------------------------
__global__ __launch_bounds__(512, 2) void attn_kernel(
    const float* __restrict__ adj, const _Float16* __restrict__ Q16,
    const _Float16* __restrict__ K16, const _Float16* __restrict__ VT16,
    _Float16* __restrict__ Opart, float* __restrict__ Mpart, float* __restrict__ Lpart)
{
  __shared__ __align__(16) _Float16 Kt[2][64 * 256];    // 2 x 32 KB  [key][d]
  __shared__ __align__(16) _Float16 Vt[2][256 * 64];    // 2 x 32 KB  [d][tok]
  __shared__ __align__(16) _Float16 Pbuf[8 * 16 * 72];  // 18 KB

  int b = blockIdx.x;
  int head = (b >> 2) & 1;
  int gs = b & 3;
  int q0 = (b >> 3) * 128;

  int tid = threadIdx.x;
  int w = tid >> 6, lane = tid & 63, quad = lane >> 4, cL = lane & 15;

  const _Float16* Qh = Q16 + head * (N_TOK * D_HID);
  const _Float16* Kh = K16 + head * (N_TOK * D_HID);
  const _Float16* Vh = VT16 + head * (N_TOK * D_HID);
  const float* adjh = adj + (size_t)head * N_TOK * N_TOK;

  int qrow = q0 + w * 16;
  int nstart = gs * 1024;
  const f32x4 z4 = {0.f, 0.f, 0.f, 0.f};

  half8 qf[8];
#pragma unroll
  for (int t = 0; t < 8; t++)
    qf[t] = *(const half8*)(Qh + (qrow + cL) * D_HID + t * 32 + quad * 8);

  f32x4 acc[16];
#pragma unroll
  for (int i = 0; i < 16; i++) acc[i] = z4;
  float m_i[4] = {-1e30f, -1e30f, -1e30f, -1e30f};
  float l_i[4] = {0.f, 0.f, 0.f, 0.f};

  _Float16* pb = Pbuf + w * (16 * 72);

  const float* adjR[4];
#pragma unroll
  for (int reg = 0; reg < 4; reg++)
    adjR[reg] = adjh + (size_t)(qrow + quad * 4 + reg) * N_TOK + nstart + cL;

  int l5 = lane >> 5, l31 = lane & 31;   // K staging: 2 rows (512B) per copy
  int l3 = lane >> 3, l7 = lane & 7;     // V staging: 8 rows (128B) per copy

  // stage K tile (64 keys x 256 d); xor-swizzled 16B chunks in 512B rows.
  auto stageK = [&](int it, _Float16* dst) {
    int n0 = nstart + it * 64;
#pragma unroll
    for (int i = 0; i < 4; i++) {
      int g = w * 4 + i;
      int rK = 2 * g + l5;
      int cK = l31 ^ (rK & 7);
      async_copy16(Kh + (size_t)(n0 + rK) * D_HID + cK * 8, dst + g * 512);
    }
  };
  // stage V tile (256 d x 64 tok); xor-swizzled 16B chunks in 128B rows.
  auto stageV = [&](int it, _Float16* dst) {
    int n0 = nstart + it * 64;
#pragma unroll
    for (int i = 0; i < 4; i++) {
      int g = w * 4 + i;
      int rV = g * 8 + l3;
      int cV = l7 ^ (rV & 7);
      async_copy16(Vh + (size_t)rV * N_TOK + n0 + cV * 8, dst + g * 512);
    }
  };
  auto loadAdj = [&](int it, float (&av)[4][4]) {
#pragma unroll
    for (int reg = 0; reg < 4; reg++)
#pragma unroll
      for (int ct = 0; ct < 4; ct++)
        av[reg][ct] = __builtin_nontemporal_load(adjR[reg] + it * 64 + ct * 16);
  };

  auto body = [&](int it, const _Float16* KC, const _Float16* VC,
                  _Float16* KN, _Float16* VN,
                  float (&avC)[4][4], float (&avN)[4][4]) {
    // prefetch tile it+1 (K+V DMA + adj) before any compute on tile it
    if (it + 1 < 16) {
      stageK(it + 1, KN);
      stageV(it + 1, VN);
      loadAdj(it + 1, avN);
    }

    // QK^T : S[16q][64k]
    f32x4 s[4];
#pragma unroll
    for (int ct = 0; ct < 4; ct++) s[ct] = z4;
    __builtin_amdgcn_s_setprio(1);
#pragma unroll
    for (int t = 0; t < 8; t++) {
#pragma unroll
      for (int ct = 0; ct < 4; ct++) {
        int rK = ct * 16 + cL;
        int ck = (t * 4 + quad) ^ (rK & 7);
        half8 kf = *(const half8*)(KC + rK * 256 + ck * 8);
        s[ct] = __builtin_amdgcn_mfma_f32_16x16x32_f16(qf[t], kf, s[ct], 0, 0, 0);
      }
    }
    __builtin_amdgcn_s_setprio(0);

    // mask + online softmax (rows = quad*4+reg, cols = ct*16+cL)
    float alpha[4];
#pragma unroll
    for (int reg = 0; reg < 4; reg++) {
#pragma unroll
      for (int ct = 0; ct < 4; ct++) s[ct][reg] *= avC[reg][ct];
      float mx = fmaxf(fmaxf(s[0][reg], s[1][reg]), fmaxf(s[2][reg], s[3][reg]));
#pragma unroll
      for (int msk = 1; msk < 16; msk <<= 1) mx = fmaxf(mx, __shfl_xor(mx, msk, 16));
      float mnew = fmaxf(m_i[reg], mx);
      alpha[reg] = __expf(m_i[reg] - mnew);
      m_i[reg] = mnew;
      float rs = 0.f;
#pragma unroll
      for (int ct = 0; ct < 4; ct++) {
        float p = __expf(s[ct][reg] - mnew);
        s[ct][reg] = p;
        rs += p;
      }
#pragma unroll
      for (int msk = 1; msk < 16; msk <<= 1) rs += __shfl_xor(rs, msk, 16);
      l_i[reg] = l_i[reg] * alpha[reg] + rs;
    }

    // P -> LDS (per-wave buffer, same-wave lgkm ordering only)
#pragma unroll
    for (int reg = 0; reg < 4; reg++)
#pragma unroll
      for (int ct = 0; ct < 4; ct++)
        pb[(quad * 4 + reg) * 72 + ct * 16 + cL] = (_Float16)s[ct][reg];

    // rescale acc only if any row's max grew (alpha==1 exactly when unchanged)
    if (__any(alpha[0] * alpha[1] * alpha[2] * alpha[3] != 1.0f)) {
#pragma unroll
      for (int dt = 0; dt < 16; dt++)
#pragma unroll
        for (int reg = 0; reg < 4; reg++)
          acc[dt][reg] *= alpha[reg];
    }

    // PV : acc[q][d] += P[q][k] * V[d][k]
    half8 pf0 = *(const half8*)(pb + cL * 72 + quad * 8);
    half8 pf1 = *(const half8*)(pb + cL * 72 + 32 + quad * 8);
    __builtin_amdgcn_s_setprio(1);
#pragma unroll
    for (int dt = 0; dt < 16; dt++) {
      int rV = dt * 16 + cL;
      int c0 = (quad) ^ (rV & 7);
      int c1 = (4 + quad) ^ (rV & 7);
      half8 v0 = *(const half8*)(VC + rV * 64 + c0 * 8);
      half8 v1 = *(const half8*)(VC + rV * 64 + c1 * 8);
      acc[dt] = __builtin_amdgcn_mfma_f32_16x16x32_f16(pf0, v0, acc[dt], 0, 0, 0);
      acc[dt] = __builtin_amdgcn_mfma_f32_16x16x32_f16(pf1, v1, acc[dt], 0, 0, 0);
    }
    __builtin_amdgcn_s_setprio(0);

    // single barrier: drains prefetch DMA (vmcnt 0) + retires KC/VC reads
    // before the next iteration's stage overwrites them.
    __syncthreads();
  };

  // prologue: tile 0 into buffer 0
  stageK(0, Kt[0]);
  stageV(0, Vt[0]);
  float avA[4][4], avB[4][4];
  loadAdj(0, avA);
  __syncthreads();

  for (int itp = 0; itp < 8; ++itp) {
    body(2 * itp,     Kt[0], Vt[0], Kt[1], Vt[1], avA, avB);
    body(2 * itp + 1, Kt[1], Vt[1], Kt[0], Vt[0], avB, avA);
  }

  int prow = (head * 4 + gs) * N_TOK + qrow + quad * 4;
#pragma unroll
  for (int reg = 0; reg < 4; reg++) {
    int row = prow + reg;
#pragma unroll
    for (int dt = 0; dt < 16; dt++)
      Opart[(size_t)row * D_HID + dt * 16 + cL] = (_Float16)acc[dt][reg];
    if (cL == 0) { Mpart[row] = m_i[reg]; Lpart[row] = l_i[reg]; }
  }
}

// ---------------------------------------------------------------------------
// final (fused with merge): per 16-row block. The 8 Opart slabs for this
// row-block (8 KB each) are first staged COALESCED into LDS (fixes R4's
// scattered 16B global reads -> ~4x HBM over-fetch on Opart), then each
// thread gathers its af[] fragments from LDS with the split weights.
// Then z = X@Wo + bo -> LayerNorm -> softmax(M@Wp + bp) -> out [4096][40].
// grid 256 x 256 thr. LDS ~150 KB (1 block/CU).
// ---------------------------------------------------------------------------
__global__ __launch_bounds__(256, 1) void final_kernel(
    const _Float16* __restrict__ Opart, const float* __restrict__ Mpart,
    const float* __restrict__ Lpart, const _Float16* __restrict__ Wot,
    const _Float16* __restrict__ Wpt, const float* __restrict__ bo,
    const float* __restrict__ gamma, const float* __restrict__ beta,
    const float* __restrict__ bp, float* __restrict__ out)
{
  __shared__ __align__(16) _Float16 Btile[512 * 64];      // 64 KB
  __shared__ __align__(16) _Float16 Ostage[8 * 16 * 264]; // 66 KB (rows padded to 264)
  __shared__ __align__(16) _Float16 Mlds[16 * 520];
  __shared__ float outs[16 * 48];
  __shared__ float lnsum[4][16], lnsq[4][16];
  __shared__ float smx[16], srl[16];

  int rowbase = blockIdx.x * 16;
  int tid = threadIdx.x, w = tid >> 6, lane = tid & 63, quad = lane >> 4, cL = lane & 15;
  const f32x4 z4 = {0.f, 0.f, 0.f, 0.f};
  int row = rowbase + cL;

  // ---- stage the 8 Opart slabs (split-major) coalesced into LDS.
  // 4096 16B units total; unit u = slab(3b) | row(4b) | col8(5b).
#pragma unroll
  for (int i = 0; i < 16; i++) {
    int u = tid + 256 * i;
    int sl = u >> 9;            // 0..7 = head*4 + split
    int r  = (u >> 5) & 15;     // row within slab
    int c8 = u & 31;            // 16B column unit
    half8 v = *(const half8*)(Opart + (size_t)(sl * N_TOK + rowbase + r) * D_HID + c8 * 8);
    *(half8*)(Ostage + (sl * 16 + r) * 264 + c8 * 8) = v;
  }

  // ---- merge weights: per-head split weights f[s]*rl for this thread's row
  float fr[2][4];
#pragma unroll
  for (int hd = 0; hd < 2; hd++) {
    float m[4], l[4];
    float mm = -1e30f;
#pragma unroll
    for (int s = 0; s < 4; s++) {
      int idx = (hd * 4 + s) * N_TOK + row;
      m[s] = Mpart[idx];
      l[s] = Lpart[idx];
      mm = fmaxf(mm, m[s]);
    }
    float f_[4], L = 0.f;
#pragma unroll
    for (int s = 0; s < 4; s++) { f_[s] = __expf(m[s] - mm); L += f_[s] * l[s]; }
    float rl = 1.0f / L;
#pragma unroll
    for (int s = 0; s < 4; s++) fr[hd][s] = f_[s] * rl;
  }

  __syncthreads();   // Ostage visible to all

  // ---- A-fragments: af[t] = X[row][t*32 + quad*8 .. +8] merged from 4 splits
  half8 af[16];
#pragma unroll
  for (int t = 0; t < 16; t++) {
    int hd = t >> 3;                       // col = hd*256 + dg
    int dg = (t & 7) * 32 + quad * 8;
    float o[8] = {0.f, 0.f, 0.f, 0.f, 0.f, 0.f, 0.f, 0.f};
#pragma unroll
    for (int s = 0; s < 4; s++) {
      half8 os = *(const half8*)(Ostage + ((hd * 4 + s) * 16 + cL) * 264 + dg);
#pragma unroll
      for (int u = 0; u < 8; u++) o[u] += (float)os[u] * fr[hd][s];
    }
#pragma unroll
    for (int u = 0; u < 8; u++) af[t][u] = (_Float16)o[u];
  }

  f32x4 acc[8];
#pragma unroll
  for (int i = 0; i < 8; i++) acc[i] = z4;

  int r8 = lane >> 3, chs = (lane & 7) ^ r8;

  for (int kc = 0; kc < 8; kc++) {
    __syncthreads();
#pragma unroll
    for (int g = 0; g < 16; g++) {
      int grow = (w * 16 + g) * 8 + r8;
      async_copy16(Wot + (size_t)grow * D_IN + kc * 64 + chs * 8, Btile + (w * 16 + g) * 512);
    }
    __syncthreads();
#pragma unroll
    for (int kk = 0; kk < 2; kk++) {
      int ch = ((kk * 4 + quad) ^ (cL & 7)) * 8;
      half8 a = af[kc * 2 + kk];
      half8 bf[8];
#pragma unroll
      for (int nt = 0; nt < 8; nt++)
        bf[nt] = *(const half8*)(Btile + (w * 128 + nt * 16 + cL) * 64 + ch);
#pragma unroll
      for (int nt = 0; nt < 8; nt++)
        acc[nt] = __builtin_amdgcn_mfma_f32_16x16x32_f16(a, bf[nt], acc[nt], 0, 0, 0);
    }
  }

  float sum[4] = {0, 0, 0, 0}, sq[4] = {0, 0, 0, 0};
#pragma unroll
  for (int nt = 0; nt < 8; nt++) {
    int col = w * 128 + nt * 16 + cL;
    float bb = bo[col];
#pragma unroll
    for (int reg = 0; reg < 4; reg++) {
      float z = acc[nt][reg] + bb;
      acc[nt][reg] = z;
      sum[reg] += z;
      sq[reg] += z * z;
    }
  }
#pragma unroll
  for (int reg = 0; reg < 4; reg++) {
#pragma unroll
    for (int msk = 1; msk < 16; msk <<= 1) {
      sum[reg] += __shfl_xor(sum[reg], msk, 16);
      sq[reg]  += __shfl_xor(sq[reg], msk, 16);
    }
  }
  if (cL == 0) {
#pragma unroll
    for (int reg = 0; reg < 4; reg++) {
      lnsum[w][quad * 4 + reg] = sum[reg];
      lnsq[w][quad * 4 + reg]  = sq[reg];
    }
  }
  __syncthreads();
  float mean[4], rstd[4];
#pragma unroll
  for (int reg = 0; reg < 4; reg++) {
    int r = quad * 4 + reg;
    float s  = lnsum[0][r] + lnsum[1][r] + lnsum[2][r] + lnsum[3][r];
    float s2 = lnsq[0][r]  + lnsq[1][r]  + lnsq[2][r]  + lnsq[3][r];
    float mu = s * (1.0f / 512.0f);
    float var = s2 * (1.0f / 512.0f) - mu * mu;
    mean[reg] = mu;
    rstd[reg] = rsqrtf(var + 1e-5f);
  }
#pragma unroll
  for (int nt = 0; nt < 8; nt++) {
    int col = w * 128 + nt * 16 + cL;
    float g = gamma[col], be = beta[col];
#pragma unroll
    for (int reg = 0; reg < 4; reg++) {
      float mval = (acc[nt][reg] - mean[reg]) * rstd[reg] * g + be;
      Mlds[(quad * 4 + reg) * 520 + col] = (_Float16)mval;
    }
  }
  __syncthreads();
  if (w < 3) {
    int jt = w;
    f32x4 a2 = z4;
#pragma unroll
    for (int t = 0; t < 16; t++) {
      half8 am = *(const half8*)(Mlds + cL * 520 + t * 32 + quad * 8);
      half8 bm = *(const half8*)(Wpt + (jt * 16 + cL) * D_IN + t * 32 + quad * 8);
      a2 = __builtin_amdgcn_mfma_f32_16x16x32_f16(am, bm, a2, 0, 0, 0);
    }
    int col = jt * 16 + cL;
    float bpv = (col < N_OUT) ? bp[col] : 0.0f;
#pragma unroll
    for (int reg = 0; reg < 4; reg++)
      outs[(quad * 4 + reg) * 48 + col] = a2[reg] + bpv;
  }
  __syncthreads();
  if (tid < 16) {
    int r = tid;
    float mx = -1e30f;
    for (int j = 0; j < N_OUT; j++) mx = fmaxf(mx, outs[r * 48 + j]);
    float ssum = 0.f;
    for (int j = 0; j < N_OUT; j++) ssum += __expf(outs[r * 48 + j] - mx);
    smx[r] = mx;
    srl[r] = 1.0f / ssum;
  }
  __syncthreads();
#pragma unroll
  for (int i = 0; i < 3; i++) {
    int lin = tid + 256 * i;
    if (lin < 16 * N_OUT) {
      int r = lin / N_OUT, col = lin % N_OUT;
      out[(size_t)(rowbase + r) * N_OUT + col] =
          __expf(outs[r * 48 + col] - smx[r]) * srl[r];
    }
  }
}

// ---------------------------------------------------------------------------
// Workspace layout (bytes, 256-aligned). Opart overlays buffers dead by attn
// time (h16, Wqt/Wkt/Wvt). V16 eliminated (VT computed directly in proj).
// Xf eliminated (merge fused into final).
// ---------------------------------------------------------------------------
#define OFF_WOT   0u
#define OFF_WPT   524288u
#define OFF_Q16   573440u
#define OFF_K16   4767744u
#define OFF_VT16  8962048u
#define OFF_MP    13156352u
#define OFF_LP    13287424u
#define OFF_OP    17612800u
// overlay (dead before attn):
#define OFF_H16   17612800u
#define OFF_WQT   21807104u
#define OFF_WKT   22331392u
#define OFF_WVT   22855680u

extern "C" void kernel_launch(void* const* d_in, const int* in_sizes, int n_in,
                              void* d_out, int out_size, void* d_ws, size_t ws_size,
                              hipStream_t stream)
{
  const float* adj   = (const float*)d_in[0];
  const float* h     = (const float*)d_in[1];
  const float* Wq    = (const float*)d_in[2];
  const float* bq    = (const float*)d_in[3];
  const float* Wk    = (const float*)d_in[4];
  const float* bk    = (const float*)d_in[5];
  const float* Wv    = (const float*)d_in[6];
  const float* bv    = (const float*)d_in[7];
  const float* Wo    = (const float*)d_in[8];
  const float* bo    = (const float*)d_in[9];
  const float* gamma = (const float*)d_in[10];
  const float* beta  = (const float*)d_in[11];
  const float* Wp    = (const float*)d_in[12];
  const float* bp    = (const float*)d_in[13];
  float* out = (float*)d_out;
  char* ws = (char*)d_ws;

  _Float16* h16   = (_Float16*)(ws + OFF_H16);
  _Float16* Wqt   = (_Float16*)(ws + OFF_WQT);
  _Float16* Wkt   = (_Float16*)(ws + OFF_WKT);
  _Float16* Wvt   = (_Float16*)(ws + OFF_WVT);
  _Float16* Wot   = (_Float16*)(ws + OFF_WOT);
  _Float16* Wpt   = (_Float16*)(ws + OFF_WPT);
  _Float16* Q16   = (_Float16*)(ws + OFF_Q16);
  _Float16* K16   = (_Float16*)(ws + OFF_K16);
  _Float16* VT16  = (_Float16*)(ws + OFF_VT16);
  _Float16* Opart = (_Float16*)(ws + OFF_OP);
  float*    Mpart = (float*)(ws + OFF_MP);
  float*    Lpart = (float*)(ws + OFF_LP);

  prep_kernel<<<1304, 256, 0, stream>>>(h, Wq, Wk, Wv, Wo, Wp,
                                        h16, Wqt, Wkt, Wvt, Wot, Wpt);
  proj_kernel<<<384, 256, 0, stream>>>(h16, Wqt, Wvt, bq, bk, bv,
                                       Q16, K16, VT16);
  attn_kernel<<<256, 512, 0, stream>>>(adj, Q16, K16, VT16, Opart, Mpart, Lpart);
  final_kernel<<<256, 256, 0, stream>>>(Opart, Mpart, Lpart, Wot, Wpt,
                                        bo, gamma, beta, bp, out);
}

// Round 7
// 291.761 us; speedup vs baseline: 5.2073x; 1.0294x over previous
//
#include <hip/hip_runtime.h>
#include <hip/hip_bf16.h>

#define N_TOK 4096
#define D_IN  512
#define D_HID 256
#define N_OUT 40

typedef _Float16 half8 __attribute__((ext_vector_type(8)));
typedef _Float16 half4 __attribute__((ext_vector_type(4)));
typedef float    f32x4 __attribute__((ext_vector_type(4)));

// async 16B/lane global->LDS DMA; lds dst is wave-uniform base (+lane*16 implicit)
__device__ __forceinline__ void async_copy16(const _Float16* g, _Float16* l) {
  __builtin_amdgcn_global_load_lds(
      (const __attribute__((address_space(1))) unsigned int*)(g),
      (__attribute__((address_space(3))) unsigned int*)(l), 16, 0, 0);
}

// ---------------------------------------------------------------------------
// prep: h -> fp16; W transposes via LDS 64x64 tiles (coalesced both sides)
// grid: 1024 (h) + 192 (Wqkv tiles) + 64 (Wo tiles) + 24 (Wp) = 1304
// ---------------------------------------------------------------------------
__device__ __forceinline__ void transpose_tile(const float* __restrict__ src, int in_ncols,
                                               _Float16* __restrict__ dst, int out_ncols,
                                               int i0, int d0, float* lds /* 64*65 */)
{
  int tid = threadIdx.x;
  int l15 = tid & 15, l4 = tid >> 4;
#pragma unroll
  for (int p = 0; p < 4; p++) {
    int ii = p * 16 + l4;
    float4 x = *(const float4*)(src + (size_t)(i0 + ii) * in_ncols + d0 + l15 * 4);
    lds[(l15 * 4 + 0) * 65 + ii] = x.x;
    lds[(l15 * 4 + 1) * 65 + ii] = x.y;
    lds[(l15 * 4 + 2) * 65 + ii] = x.z;
    lds[(l15 * 4 + 3) * 65 + ii] = x.w;
  }
  __syncthreads();
  int dd = tid >> 2, chunk = tid & 3;
  half8 o0, o1;
#pragma unroll
  for (int j = 0; j < 8; j++) o0[j] = (_Float16)lds[dd * 65 + chunk * 16 + j];
#pragma unroll
  for (int j = 0; j < 8; j++) o1[j] = (_Float16)lds[dd * 65 + chunk * 16 + 8 + j];
  *(half8*)(dst + (size_t)(d0 + dd) * out_ncols + i0 + chunk * 16) = o0;
  *(half8*)(dst + (size_t)(d0 + dd) * out_ncols + i0 + chunk * 16 + 8) = o1;
}

__global__ void prep_kernel(const float* __restrict__ h, const float* __restrict__ Wq,
                            const float* __restrict__ Wk, const float* __restrict__ Wv,
                            const float* __restrict__ Wo, const float* __restrict__ Wp,
                            _Float16* __restrict__ h16, _Float16* __restrict__ Wqt,
                            _Float16* __restrict__ Wkt, _Float16* __restrict__ Wvt,
                            _Float16* __restrict__ Wot, _Float16* __restrict__ Wpt)
{
  __shared__ float lds[64 * 65];
  int b = blockIdx.x, tid = threadIdx.x;
  if (b < 1024) {                              // h -> h16 (4096x512)
    int base = b * 2048 + tid * 8;
    float4 x0 = *(const float4*)(h + base);
    float4 x1 = *(const float4*)(h + base + 4);
    half8 o;
    o[0]=(_Float16)x0.x; o[1]=(_Float16)x0.y; o[2]=(_Float16)x0.z; o[3]=(_Float16)x0.w;
    o[4]=(_Float16)x1.x; o[5]=(_Float16)x1.y; o[6]=(_Float16)x1.z; o[7]=(_Float16)x1.w;
    *(half8*)(h16 + base) = o;
  } else if (b < 1216) {                       // Wq/Wk/Wv transpose, 64x64 tiles
    int t = b - 1024;                          // 0..191
    int mat = t >> 5;                          // 0..5
    int m = mat >> 1, head = mat & 1;
    const float* W = (m==0 ? Wq : (m==1 ? Wk : Wv)) + head * (D_IN * D_HID);
    _Float16* Wt   = (m==0 ? Wqt : (m==1 ? Wkt : Wvt)) + head * (D_IN * D_HID);
    int tt = t & 31;
    int i0 = (tt >> 2) * 64, d0 = (tt & 3) * 64;
    transpose_tile(W, D_HID, Wt, D_IN, i0, d0, lds);
  } else if (b < 1280) {                       // Wo transpose (512x512)
    int t = b - 1216;                          // 0..63
    int i0 = (t >> 3) * 64, d0 = (t & 7) * 64;
    transpose_tile(Wo, D_IN, Wot, D_IN, i0, d0, lds);
  } else {                                     // Wp transpose+pad to [48][512]
    int blk = b - 1280;                        // 0..23
    int idx = blk * 1024 + tid * 4;
    int j = idx >> 9, i = idx & 511;
    half4 o;
#pragma unroll
    for (int u = 0; u < 4; u++)
      o[u] = (j < N_OUT) ? (_Float16)Wp[(i + u) * N_OUT + j] : (_Float16)0.f;
    *(half4*)(Wpt + j * D_IN + i) = o;
  }
}

// ---------------------------------------------------------------------------
// proj: unified 128x128-tile GEMM, BK=64, double-buffered LDS with a single
// barrier per kc. Blocks 0..255: Q/K = h16 @ [Wqt;Wkt]. 256..383: VT direct.
// ---------------------------------------------------------------------------
__global__ __launch_bounds__(256, 2) void proj_kernel(
    const _Float16* __restrict__ h16, const _Float16* __restrict__ W6 /*Wqt base*/,
    const _Float16* __restrict__ Wvt,
    const float* __restrict__ bq, const float* __restrict__ bk,
    const float* __restrict__ bv,
    _Float16* __restrict__ Q16, _Float16* __restrict__ K16,
    _Float16* __restrict__ VT16)
{
  __shared__ __align__(16) _Float16 Atile[2][128 * 64];   // 2 x 16 KB
  __shared__ __align__(16) _Float16 Btile[2][128 * 64];   // 2 x 16 KB

  int b = blockIdx.x;
  int tid = threadIdx.x, w = tid >> 6, lane = tid & 63, quad = lane >> 4, cL = lane & 15;
  int wr = w >> 1, wc = w & 1;

  const _Float16 *Asrc, *Bsrc;
  int isV;
  int m0 = 0, n0 = 0, head = 0, mh = 0;
  if (b < 256) {
    isV = 0;
    m0 = (b >> 3) * 128;
    int ct = b & 7;
    mh = ct >> 1;                       // 0,1: Q heads; 2,3: K heads
    n0 = (ct & 1) * 128;
    Asrc = h16 + (size_t)m0 * D_IN;
    Bsrc = W6 + (size_t)(ct * 128) * D_IN;
  } else {
    isV = 1;
    int t = b - 256;
    head = t >> 6;
    int tt = t & 63;
    m0 = (tt >> 5) * 128;               // d-half base
    n0 = (tt & 31) * 128;               // token base
    Asrc = Wvt + (size_t)head * (D_HID * D_IN) + (size_t)m0 * D_IN;
    Bsrc = h16 + (size_t)n0 * D_IN;
  }

  const f32x4 z4 = {0.f, 0.f, 0.f, 0.f};
  f32x4 acc[4][4];
#pragma unroll
  for (int i = 0; i < 4; i++)
#pragma unroll
    for (int j = 0; j < 4; j++) acc[i][j] = z4;

  int r8 = lane >> 3, chs = (lane & 7) ^ r8;   // staging row-in-8 / swizzled chunk

  auto stage = [&](int kc, int pb) {
#pragma unroll
    for (int g = 0; g < 4; g++) {
      int row = (w * 4 + g) * 8 + r8;
      async_copy16(Asrc + (size_t)row * D_IN + kc * 64 + chs * 8, Atile[pb] + (w * 4 + g) * 512);
      async_copy16(Bsrc + (size_t)row * D_IN + kc * 64 + chs * 8, Btile[pb] + (w * 4 + g) * 512);
    }
  };

  stage(0, 0);
  __syncthreads();   // drain first tile

  for (int kc = 0; kc < 8; kc++) {
    int cur = kc & 1;
    if (kc + 1 < 8) stage(kc + 1, cur ^ 1);
#pragma unroll
    for (int kk = 0; kk < 2; kk++) {
      int ch = ((kk * 4 + quad) ^ (cL & 7)) * 8;
      half8 a[4], bf[4];
#pragma unroll
      for (int mt = 0; mt < 4; mt++)
        a[mt] = *(const half8*)(Atile[cur] + (wr * 64 + mt * 16 + cL) * 64 + ch);
#pragma unroll
      for (int nt = 0; nt < 4; nt++)
        bf[nt] = *(const half8*)(Btile[cur] + (wc * 64 + nt * 16 + cL) * 64 + ch);
#pragma unroll
      for (int mt = 0; mt < 4; mt++)
#pragma unroll
        for (int nt = 0; nt < 4; nt++)
          acc[mt][nt] = __builtin_amdgcn_mfma_f32_16x16x32_f16(a[mt], bf[nt], acc[mt][nt], 0, 0, 0);
    }
    __syncthreads();   // retire reads of [cur] + drain prefetch DMA into [cur^1]
  }

  if (!isV) {
    _Float16* Out = (mh < 2 ? Q16 + (size_t)mh * (N_TOK * D_HID)
                            : K16 + (size_t)(mh - 2) * (N_TOK * D_HID));
    const float* bias = (mh < 2 ? bq + mh * D_HID : bk + (mh - 2) * D_HID);
#pragma unroll
    for (int mt = 0; mt < 4; mt++) {
      int row = m0 + wr * 64 + mt * 16 + quad * 4;
#pragma unroll
      for (int nt = 0; nt < 4; nt++) {
        int colg = n0 + wc * 64 + nt * 16 + cL;
        float bb = bias[colg];
#pragma unroll
        for (int reg = 0; reg < 4; reg++)
          Out[(size_t)(row + reg) * D_HID + colg] = (_Float16)(acc[mt][nt][reg] + bb);
      }
    }
  } else {
    _Float16* VTh = VT16 + (size_t)head * (N_TOK * D_HID);
    const float* bvh = bv + head * D_HID;
#pragma unroll
    for (int mt = 0; mt < 4; mt++) {
      int d0r = m0 + wr * 64 + mt * 16 + quad * 4;
      float bvv[4];
#pragma unroll
      for (int reg = 0; reg < 4; reg++) bvv[reg] = bvh[d0r + reg];
#pragma unroll
      for (int nt = 0; nt < 4; nt++) {
        int tok = n0 + wc * 64 + nt * 16 + cL;
#pragma unroll
        for (int reg = 0; reg < 4; reg++)
          VTh[(size_t)(d0r + reg) * N_TOK + tok] = (_Float16)(acc[mt][nt][reg] + bvv[reg]);
      }
    }
  }
}

// ---------------------------------------------------------------------------
// attn: flash attention with SWAPPED QK^T (S^T = mfma(K,Q)) so the masked
// online softmax is lane-local: lane (cL,quad) holds S[q=cL][k=ct*16+quad*4+reg]
// for 16 k-values in registers. Row max/sum = in-register reduce + 2+2
// shfl_xor rounds (xor 16/32) — replaces the previous 32 ds_swizzle ops and
// 8-deep dependent shuffle chain per wave-iteration. P is written to Pbuf as
// [q][k] (same semantic layout as before), so PV / staging / acc / output
// writes are unchanged from the verified R6 kernel. alpha is redistributed
// from q=cL lanes to acc's q=quad*4+reg rows by 4 shfl ops, only when the
// rescale vote fires. 512 thr / 8 waves, grid 256 = 1 block/CU, K+V dbuf,
// one barrier per iteration, setprio around MFMA clusters.
// ---------------------------------------------------------------------------
__global__ __launch_bounds__(512, 2) void attn_kernel(
    const float* __restrict__ adj, const _Float16* __restrict__ Q16,
    const _Float16* __restrict__ K16, const _Float16* __restrict__ VT16,
    _Float16* __restrict__ Opart, float* __restrict__ Mpart, float* __restrict__ Lpart)
{
  __shared__ __align__(16) _Float16 Kt[2][64 * 256];    // 2 x 32 KB  [key][d]
  __shared__ __align__(16) _Float16 Vt[2][256 * 64];    // 2 x 32 KB  [d][tok]
  __shared__ __align__(16) _Float16 Pbuf[8 * 16 * 72];  // 18 KB

  int b = blockIdx.x;
  int head = (b >> 2) & 1;
  int gs = b & 3;
  int q0 = (b >> 3) * 128;

  int tid = threadIdx.x;
  int w = tid >> 6, lane = tid & 63, quad = lane >> 4, cL = lane & 15;

  const _Float16* Qh = Q16 + head * (N_TOK * D_HID);
  const _Float16* Kh = K16 + head * (N_TOK * D_HID);
  const _Float16* Vh = VT16 + head * (N_TOK * D_HID);
  const float* adjh = adj + (size_t)head * N_TOK * N_TOK;

  int qrow = q0 + w * 16;
  int nstart = gs * 1024;
  const f32x4 z4 = {0.f, 0.f, 0.f, 0.f};

  half8 qf[8];
#pragma unroll
  for (int t = 0; t < 8; t++)
    qf[t] = *(const half8*)(Qh + (qrow + cL) * D_HID + t * 32 + quad * 8);

  f32x4 acc[16];
#pragma unroll
  for (int i = 0; i < 16; i++) acc[i] = z4;
  float m_q = -1e30f;   // running max for row q=cL (replicated across quads)
  float l_q = 0.f;      // running sum for row q=cL

  _Float16* pb = Pbuf + w * (16 * 72);

  // adj: lane (cL,quad) needs adj[qrow+cL][n + ct*16 + quad*4 + reg]
  const float* adjRT = adjh + (size_t)(qrow + cL) * N_TOK + nstart + quad * 4;

  int l5 = lane >> 5, l31 = lane & 31;   // K staging: 2 rows (512B) per copy
  int l3 = lane >> 3, l7 = lane & 7;     // V staging: 8 rows (128B) per copy

  // stage K tile (64 keys x 256 d); xor-swizzled 16B chunks in 512B rows.
  auto stageK = [&](int it, _Float16* dst) {
    int n0 = nstart + it * 64;
#pragma unroll
    for (int i = 0; i < 4; i++) {
      int g = w * 4 + i;
      int rK = 2 * g + l5;
      int cK = l31 ^ (rK & 7);
      async_copy16(Kh + (size_t)(n0 + rK) * D_HID + cK * 8, dst + g * 512);
    }
  };
  // stage V tile (256 d x 64 tok); xor-swizzled 16B chunks in 128B rows.
  auto stageV = [&](int it, _Float16* dst) {
    int n0 = nstart + it * 64;
#pragma unroll
    for (int i = 0; i < 4; i++) {
      int g = w * 4 + i;
      int rV = g * 8 + l3;
      int cV = l7 ^ (rV & 7);
      async_copy16(Vh + (size_t)rV * N_TOK + n0 + cV * 8, dst + g * 512);
    }
  };
  auto loadAdj = [&](int it, float (&av)[4][4]) {
#pragma unroll
    for (int ct = 0; ct < 4; ct++)
#pragma unroll
      for (int reg = 0; reg < 4; reg++)
        av[ct][reg] = __builtin_nontemporal_load(adjRT + it * 64 + ct * 16 + reg);
  };

  auto body = [&](int it, const _Float16* KC, const _Float16* VC,
                  _Float16* KN, _Float16* VN,
                  float (&avC)[4][4], float (&avN)[4][4]) {
    // prefetch tile it+1 (K+V DMA + adj) before any compute on tile it
    if (it + 1 < 16) {
      stageK(it + 1, KN);
      stageV(it + 1, VN);
      loadAdj(it + 1, avN);
    }

    // QK^T swapped: sT[ct] = mfma(K, Q) -> lane holds S[q=cL][k=ct*16+quad*4+reg]
    f32x4 sT[4];
#pragma unroll
    for (int ct = 0; ct < 4; ct++) sT[ct] = z4;
    __builtin_amdgcn_s_setprio(1);
#pragma unroll
    for (int t = 0; t < 8; t++) {
#pragma unroll
      for (int ct = 0; ct < 4; ct++) {
        int rK = ct * 16 + cL;
        int ck = (t * 4 + quad) ^ (rK & 7);
        half8 kf = *(const half8*)(KC + rK * 256 + ck * 8);
        sT[ct] = __builtin_amdgcn_mfma_f32_16x16x32_f16(kf, qf[t], sT[ct], 0, 0, 0);
      }
    }
    __builtin_amdgcn_s_setprio(0);

    // mask + lane-local row max over the 16 in-register k-values
    float mrow = -1e30f;
#pragma unroll
    for (int ct = 0; ct < 4; ct++)
#pragma unroll
      for (int reg = 0; reg < 4; reg++) {
        float v = sT[ct][reg] * avC[ct][reg];
        sT[ct][reg] = v;
        mrow = fmaxf(mrow, v);
      }
    // cross-quad reduce (lanes sharing cL): 2 rounds
    mrow = fmaxf(mrow, __shfl_xor(mrow, 16, 64));
    mrow = fmaxf(mrow, __shfl_xor(mrow, 32, 64));

    float mnew = fmaxf(m_q, mrow);
    float alpha = __expf(m_q - mnew);
    m_q = mnew;

    float rs = 0.f;
#pragma unroll
    for (int ct = 0; ct < 4; ct++)
#pragma unroll
      for (int reg = 0; reg < 4; reg++) {
        float p = __expf(sT[ct][reg] - mnew);
        sT[ct][reg] = p;
        rs += p;
      }
    rs += __shfl_xor(rs, 16, 64);
    rs += __shfl_xor(rs, 32, 64);
    l_q = l_q * alpha + rs;

    // P -> LDS as [q=cL][k] (same [q][k] layout PV consumed before)
#pragma unroll
    for (int ct = 0; ct < 4; ct++)
#pragma unroll
      for (int reg = 0; reg < 4; reg++)
        pb[cL * 72 + ct * 16 + quad * 4 + reg] = (_Float16)sT[ct][reg];

    // rescale acc only if any row's max grew; acc rows are q=quad*4+reg, so
    // fetch alpha from the lane holding that q (same quad group, cL=q).
    if (__any(alpha != 1.0f)) {
      float alphaA[4];
#pragma unroll
      for (int reg = 0; reg < 4; reg++)
        alphaA[reg] = __shfl(alpha, (lane & 48) | (quad * 4 + reg), 64);
#pragma unroll
      for (int dt = 0; dt < 16; dt++)
#pragma unroll
        for (int reg = 0; reg < 4; reg++)
          acc[dt][reg] *= alphaA[reg];
    }

    // PV : acc[q][d] += P[q][k] * V[d][k]  (unchanged)
    half8 pf0 = *(const half8*)(pb + cL * 72 + quad * 8);
    half8 pf1 = *(const half8*)(pb + cL * 72 + 32 + quad * 8);
    __builtin_amdgcn_s_setprio(1);
#pragma unroll
    for (int dt = 0; dt < 16; dt++) {
      int rV = dt * 16 + cL;
      int c0 = (quad) ^ (rV & 7);
      int c1 = (4 + quad) ^ (rV & 7);
      half8 v0 = *(const half8*)(VC + rV * 64 + c0 * 8);
      half8 v1 = *(const half8*)(VC + rV * 64 + c1 * 8);
      acc[dt] = __builtin_amdgcn_mfma_f32_16x16x32_f16(pf0, v0, acc[dt], 0, 0, 0);
      acc[dt] = __builtin_amdgcn_mfma_f32_16x16x32_f16(pf1, v1, acc[dt], 0, 0, 0);
    }
    __builtin_amdgcn_s_setprio(0);

    // single barrier: drains prefetch DMA (vmcnt 0) + retires KC/VC reads
    // before the next iteration's stage overwrites them.
    __syncthreads();
  };

  // prologue: tile 0 into buffer 0
  stageK(0, Kt[0]);
  stageV(0, Vt[0]);
  float avA[4][4], avB[4][4];
  loadAdj(0, avA);
  __syncthreads();

  for (int itp = 0; itp < 8; ++itp) {
    body(2 * itp,     Kt[0], Vt[0], Kt[1], Vt[1], avA, avB);
    body(2 * itp + 1, Kt[1], Vt[1], Kt[0], Vt[0], avB, avA);
  }

  int prowbase = (head * 4 + gs) * N_TOK + qrow;
#pragma unroll
  for (int reg = 0; reg < 4; reg++) {
    int row = prowbase + quad * 4 + reg;
#pragma unroll
    for (int dt = 0; dt < 16; dt++)
      Opart[(size_t)row * D_HID + dt * 16 + cL] = (_Float16)acc[dt][reg];
  }
  // m/l live per-lane for q=cL (replicated across quads): quad 0 writes.
  if (quad == 0) {
    Mpart[prowbase + cL] = m_q;
    Lpart[prowbase + cL] = l_q;
  }
}

// ---------------------------------------------------------------------------
// final (fused with merge): per 16-row block. The 8 Opart slabs for this
// row-block are staged COALESCED into LDS, then each thread gathers its af[]
// fragments from LDS with the split weights. Then z = X@Wo + bo -> LayerNorm
// -> softmax(M@Wp + bp) -> out [4096][40]. grid 256 x 256 thr. LDS ~150 KB.
// ---------------------------------------------------------------------------
__global__ __launch_bounds__(256, 1) void final_kernel(
    const _Float16* __restrict__ Opart, const float* __restrict__ Mpart,
    const float* __restrict__ Lpart, const _Float16* __restrict__ Wot,
    const _Float16* __restrict__ Wpt, const float* __restrict__ bo,
    const float* __restrict__ gamma, const float* __restrict__ beta,
    const float* __restrict__ bp, float* __restrict__ out)
{
  __shared__ __align__(16) _Float16 Btile[512 * 64];      // 64 KB
  __shared__ __align__(16) _Float16 Ostage[8 * 16 * 264]; // 66 KB (rows padded to 264)
  __shared__ __align__(16) _Float16 Mlds[16 * 520];
  __shared__ float outs[16 * 48];
  __shared__ float lnsum[4][16], lnsq[4][16];
  __shared__ float smx[16], srl[16];

  int rowbase = blockIdx.x * 16;
  int tid = threadIdx.x, w = tid >> 6, lane = tid & 63, quad = lane >> 4, cL = lane & 15;
  const f32x4 z4 = {0.f, 0.f, 0.f, 0.f};
  int row = rowbase + cL;

  // ---- stage the 8 Opart slabs (split-major) coalesced into LDS.
#pragma unroll
  for (int i = 0; i < 16; i++) {
    int u = tid + 256 * i;
    int sl = u >> 9;            // 0..7 = head*4 + split
    int r  = (u >> 5) & 15;     // row within slab
    int c8 = u & 31;            // 16B column unit
    half8 v = *(const half8*)(Opart + (size_t)(sl * N_TOK + rowbase + r) * D_HID + c8 * 8);
    *(half8*)(Ostage + (sl * 16 + r) * 264 + c8 * 8) = v;
  }

  // ---- merge weights: per-head split weights f[s]*rl for this thread's row
  float fr[2][4];
#pragma unroll
  for (int hd = 0; hd < 2; hd++) {
    float m[4], l[4];
    float mm = -1e30f;
#pragma unroll
    for (int s = 0; s < 4; s++) {
      int idx = (hd * 4 + s) * N_TOK + row;
      m[s] = Mpart[idx];
      l[s] = Lpart[idx];
      mm = fmaxf(mm, m[s]);
    }
    float f_[4], L = 0.f;
#pragma unroll
    for (int s = 0; s < 4; s++) { f_[s] = __expf(m[s] - mm); L += f_[s] * l[s]; }
    float rl = 1.0f / L;
#pragma unroll
    for (int s = 0; s < 4; s++) fr[hd][s] = f_[s] * rl;
  }

  __syncthreads();   // Ostage visible to all

  // ---- A-fragments: af[t] = X[row][t*32 + quad*8 .. +8] merged from 4 splits
  half8 af[16];
#pragma unroll
  for (int t = 0; t < 16; t++) {
    int hd = t >> 3;                       // col = hd*256 + dg
    int dg = (t & 7) * 32 + quad * 8;
    float o[8] = {0.f, 0.f, 0.f, 0.f, 0.f, 0.f, 0.f, 0.f};
#pragma unroll
    for (int s = 0; s < 4; s++) {
      half8 os = *(const half8*)(Ostage + ((hd * 4 + s) * 16 + cL) * 264 + dg);
#pragma unroll
      for (int u = 0; u < 8; u++) o[u] += (float)os[u] * fr[hd][s];
    }
#pragma unroll
    for (int u = 0; u < 8; u++) af[t][u] = (_Float16)o[u];
  }

  f32x4 acc[8];
#pragma unroll
  for (int i = 0; i < 8; i++) acc[i] = z4;

  int r8 = lane >> 3, chs = (lane & 7) ^ r8;

  for (int kc = 0; kc < 8; kc++) {
    __syncthreads();
#pragma unroll
    for (int g = 0; g < 16; g++) {
      int grow = (w * 16 + g) * 8 + r8;
      async_copy16(Wot + (size_t)grow * D_IN + kc * 64 + chs * 8, Btile + (w * 16 + g) * 512);
    }
    __syncthreads();
#pragma unroll
    for (int kk = 0; kk < 2; kk++) {
      int ch = ((kk * 4 + quad) ^ (cL & 7)) * 8;
      half8 a = af[kc * 2 + kk];
      half8 bf[8];
#pragma unroll
      for (int nt = 0; nt < 8; nt++)
        bf[nt] = *(const half8*)(Btile + (w * 128 + nt * 16 + cL) * 64 + ch);
#pragma unroll
      for (int nt = 0; nt < 8; nt++)
        acc[nt] = __builtin_amdgcn_mfma_f32_16x16x32_f16(a, bf[nt], acc[nt], 0, 0, 0);
    }
  }

  float sum[4] = {0, 0, 0, 0}, sq[4] = {0, 0, 0, 0};
#pragma unroll
  for (int nt = 0; nt < 8; nt++) {
    int col = w * 128 + nt * 16 + cL;
    float bb = bo[col];
#pragma unroll
    for (int reg = 0; reg < 4; reg++) {
      float z = acc[nt][reg] + bb;
      acc[nt][reg] = z;
      sum[reg] += z;
      sq[reg] += z * z;
    }
  }
#pragma unroll
  for (int reg = 0; reg < 4; reg++) {
#pragma unroll
    for (int msk = 1; msk < 16; msk <<= 1) {
      sum[reg] += __shfl_xor(sum[reg], msk, 16);
      sq[reg]  += __shfl_xor(sq[reg], msk, 16);
    }
  }
  if (cL == 0) {
#pragma unroll
    for (int reg = 0; reg < 4; reg++) {
      lnsum[w][quad * 4 + reg] = sum[reg];
      lnsq[w][quad * 4 + reg]  = sq[reg];
    }
  }
  __syncthreads();
  float mean[4], rstd[4];
#pragma unroll
  for (int reg = 0; reg < 4; reg++) {
    int r = quad * 4 + reg;
    float s  = lnsum[0][r] + lnsum[1][r] + lnsum[2][r] + lnsum[3][r];
    float s2 = lnsq[0][r]  + lnsq[1][r]  + lnsq[2][r]  + lnsq[3][r];
    float mu = s * (1.0f / 512.0f);
    float var = s2 * (1.0f / 512.0f) - mu * mu;
    mean[reg] = mu;
    rstd[reg] = rsqrtf(var + 1e-5f);
  }
#pragma unroll
  for (int nt = 0; nt < 8; nt++) {
    int col = w * 128 + nt * 16 + cL;
    float g = gamma[col], be = beta[col];
#pragma unroll
    for (int reg = 0; reg < 4; reg++) {
      float mval = (acc[nt][reg] - mean[reg]) * rstd[reg] * g + be;
      Mlds[(quad * 4 + reg) * 520 + col] = (_Float16)mval;
    }
  }
  __syncthreads();
  if (w < 3) {
    int jt = w;
    f32x4 a2 = z4;
#pragma unroll
    for (int t = 0; t < 16; t++) {
      half8 am = *(const half8*)(Mlds + cL * 520 + t * 32 + quad * 8);
      half8 bm = *(const half8*)(Wpt + (jt * 16 + cL) * D_IN + t * 32 + quad * 8);
      a2 = __builtin_amdgcn_mfma_f32_16x16x32_f16(am, bm, a2, 0, 0, 0);
    }
    int col = jt * 16 + cL;
    float bpv = (col < N_OUT) ? bp[col] : 0.0f;
#pragma unroll
    for (int reg = 0; reg < 4; reg++)
      outs[(quad * 4 + reg) * 48 + col] = a2[reg] + bpv;
  }
  __syncthreads();
  if (tid < 16) {
    int r = tid;
    float mx = -1e30f;
    for (int j = 0; j < N_OUT; j++) mx = fmaxf(mx, outs[r * 48 + j]);
    float ssum = 0.f;
    for (int j = 0; j < N_OUT; j++) ssum += __expf(outs[r * 48 + j] - mx);
    smx[r] = mx;
    srl[r] = 1.0f / ssum;
  }
  __syncthreads();
#pragma unroll
  for (int i = 0; i < 3; i++) {
    int lin = tid + 256 * i;
    if (lin < 16 * N_OUT) {
      int r = lin / N_OUT, col = lin % N_OUT;
      out[(size_t)(rowbase + r) * N_OUT + col] =
          __expf(outs[r * 48 + col] - smx[r]) * srl[r];
    }
  }
}

// ---------------------------------------------------------------------------
// Workspace layout (bytes, 256-aligned). Opart overlays buffers dead by attn
// time (h16, Wqt/Wkt/Wvt). V16 eliminated (VT computed directly in proj).
// Xf eliminated (merge fused into final).
// ---------------------------------------------------------------------------
#define OFF_WOT   0u
#define OFF_WPT   524288u
#define OFF_Q16   573440u
#define OFF_K16   4767744u
#define OFF_VT16  8962048u
#define OFF_MP    13156352u
#define OFF_LP    13287424u
#define OFF_OP    17612800u
// overlay (dead before attn):
#define OFF_H16   17612800u
#define OFF_WQT   21807104u
#define OFF_WKT   22331392u
#define OFF_WVT   22855680u

extern "C" void kernel_launch(void* const* d_in, const int* in_sizes, int n_in,
                              void* d_out, int out_size, void* d_ws, size_t ws_size,
                              hipStream_t stream)
{
  const float* adj   = (const float*)d_in[0];
  const float* h     = (const float*)d_in[1];
  const float* Wq    = (const float*)d_in[2];
  const float* bq    = (const float*)d_in[3];
  const float* Wk    = (const float*)d_in[4];
  const float* bk    = (const float*)d_in[5];
  const float* Wv    = (const float*)d_in[6];
  const float* bv    = (const float*)d_in[7];
  const float* Wo    = (const float*)d_in[8];
  const float* bo    = (const float*)d_in[9];
  const float* gamma = (const float*)d_in[10];
  const float* beta  = (const float*)d_in[11];
  const float* Wp    = (const float*)d_in[12];
  const float* bp    = (const float*)d_in[13];
  float* out = (float*)d_out;
  char* ws = (char*)d_ws;

  _Float16* h16   = (_Float16*)(ws + OFF_H16);
  _Float16* Wqt   = (_Float16*)(ws + OFF_WQT);
  _Float16* Wkt   = (_Float16*)(ws + OFF_WKT);
  _Float16* Wvt   = (_Float16*)(ws + OFF_WVT);
  _Float16* Wot   = (_Float16*)(ws + OFF_WOT);
  _Float16* Wpt   = (_Float16*)(ws + OFF_WPT);
  _Float16* Q16   = (_Float16*)(ws + OFF_Q16);
  _Float16* K16   = (_Float16*)(ws + OFF_K16);
  _Float16* VT16  = (_Float16*)(ws + OFF_VT16);
  _Float16* Opart = (_Float16*)(ws + OFF_OP);
  float*    Mpart = (float*)(ws + OFF_MP);
  float*    Lpart = (float*)(ws + OFF_LP);

  prep_kernel<<<1304, 256, 0, stream>>>(h, Wq, Wk, Wv, Wo, Wp,
                                        h16, Wqt, Wkt, Wvt, Wot, Wpt);
  proj_kernel<<<384, 256, 0, stream>>>(h16, Wqt, Wvt, bq, bk, bv,
                                       Q16, K16, VT16);
  attn_kernel<<<256, 512, 0, stream>>>(adj, Q16, K16, VT16, Opart, Mpart, Lpart);
  final_kernel<<<256, 256, 0, stream>>>(Opart, Mpart, Lpart, Wot, Wpt,
                                        bo, gamma, beta, bp, out);
}

// Round 8
// 290.263 us; speedup vs baseline: 5.2342x; 1.0052x over previous
//
#include <hip/hip_runtime.h>
#include <hip/hip_bf16.h>

#define N_TOK 4096
#define D_IN  512
#define D_HID 256
#define N_OUT 40

typedef _Float16 half8 __attribute__((ext_vector_type(8)));
typedef _Float16 half4 __attribute__((ext_vector_type(4)));
typedef float    f32x4 __attribute__((ext_vector_type(4)));

// async 16B/lane global->LDS DMA; lds dst is wave-uniform base (+lane*16 implicit)
__device__ __forceinline__ void async_copy16(const _Float16* g, _Float16* l) {
  __builtin_amdgcn_global_load_lds(
      (const __attribute__((address_space(1))) unsigned int*)(g),
      (__attribute__((address_space(3))) unsigned int*)(l), 16, 0, 0);
}

// ---------------------------------------------------------------------------
// prep: h -> fp16; W transposes via LDS 64x64 tiles (coalesced both sides)
// grid: 1024 (h) + 192 (Wqkv tiles) + 64 (Wo tiles) + 24 (Wp) = 1304
// ---------------------------------------------------------------------------
__device__ __forceinline__ void transpose_tile(const float* __restrict__ src, int in_ncols,
                                               _Float16* __restrict__ dst, int out_ncols,
                                               int i0, int d0, float* lds /* 64*65 */)
{
  int tid = threadIdx.x;
  int l15 = tid & 15, l4 = tid >> 4;
#pragma unroll
  for (int p = 0; p < 4; p++) {
    int ii = p * 16 + l4;
    float4 x = *(const float4*)(src + (size_t)(i0 + ii) * in_ncols + d0 + l15 * 4);
    lds[(l15 * 4 + 0) * 65 + ii] = x.x;
    lds[(l15 * 4 + 1) * 65 + ii] = x.y;
    lds[(l15 * 4 + 2) * 65 + ii] = x.z;
    lds[(l15 * 4 + 3) * 65 + ii] = x.w;
  }
  __syncthreads();
  int dd = tid >> 2, chunk = tid & 3;
  half8 o0, o1;
#pragma unroll
  for (int j = 0; j < 8; j++) o0[j] = (_Float16)lds[dd * 65 + chunk * 16 + j];
#pragma unroll
  for (int j = 0; j < 8; j++) o1[j] = (_Float16)lds[dd * 65 + chunk * 16 + 8 + j];
  *(half8*)(dst + (size_t)(d0 + dd) * out_ncols + i0 + chunk * 16) = o0;
  *(half8*)(dst + (size_t)(d0 + dd) * out_ncols + i0 + chunk * 16 + 8) = o1;
}

__global__ void prep_kernel(const float* __restrict__ h, const float* __restrict__ Wq,
                            const float* __restrict__ Wk, const float* __restrict__ Wv,
                            const float* __restrict__ Wo, const float* __restrict__ Wp,
                            _Float16* __restrict__ h16, _Float16* __restrict__ Wqt,
                            _Float16* __restrict__ Wkt, _Float16* __restrict__ Wvt,
                            _Float16* __restrict__ Wot, _Float16* __restrict__ Wpt)
{
  __shared__ float lds[64 * 65];
  int b = blockIdx.x, tid = threadIdx.x;
  if (b < 1024) {                              // h -> h16 (4096x512)
    int base = b * 2048 + tid * 8;
    float4 x0 = *(const float4*)(h + base);
    float4 x1 = *(const float4*)(h + base + 4);
    half8 o;
    o[0]=(_Float16)x0.x; o[1]=(_Float16)x0.y; o[2]=(_Float16)x0.z; o[3]=(_Float16)x0.w;
    o[4]=(_Float16)x1.x; o[5]=(_Float16)x1.y; o[6]=(_Float16)x1.z; o[7]=(_Float16)x1.w;
    *(half8*)(h16 + base) = o;
  } else if (b < 1216) {                       // Wq/Wk/Wv transpose, 64x64 tiles
    int t = b - 1024;                          // 0..191
    int mat = t >> 5;                          // 0..5
    int m = mat >> 1, head = mat & 1;
    const float* W = (m==0 ? Wq : (m==1 ? Wk : Wv)) + head * (D_IN * D_HID);
    _Float16* Wt   = (m==0 ? Wqt : (m==1 ? Wkt : Wvt)) + head * (D_IN * D_HID);
    int tt = t & 31;
    int i0 = (tt >> 2) * 64, d0 = (tt & 3) * 64;
    transpose_tile(W, D_HID, Wt, D_IN, i0, d0, lds);
  } else if (b < 1280) {                       // Wo transpose (512x512)
    int t = b - 1216;                          // 0..63
    int i0 = (t >> 3) * 64, d0 = (t & 7) * 64;
    transpose_tile(Wo, D_IN, Wot, D_IN, i0, d0, lds);
  } else {                                     // Wp transpose+pad to [48][512]
    int blk = b - 1280;                        // 0..23
    int idx = blk * 1024 + tid * 4;
    int j = idx >> 9, i = idx & 511;
    half4 o;
#pragma unroll
    for (int u = 0; u < 4; u++)
      o[u] = (j < N_OUT) ? (_Float16)Wp[(i + u) * N_OUT + j] : (_Float16)0.f;
    *(half4*)(Wpt + j * D_IN + i) = o;
  }
}

// ---------------------------------------------------------------------------
// proj: unified 128x128-tile GEMM, BK=64, double-buffered LDS with a single
// barrier per kc. Blocks 0..255: Q/K = h16 @ [Wqt;Wkt]. 256..383: VT direct.
// ---------------------------------------------------------------------------
__global__ __launch_bounds__(256, 2) void proj_kernel(
    const _Float16* __restrict__ h16, const _Float16* __restrict__ W6 /*Wqt base*/,
    const _Float16* __restrict__ Wvt,
    const float* __restrict__ bq, const float* __restrict__ bk,
    const float* __restrict__ bv,
    _Float16* __restrict__ Q16, _Float16* __restrict__ K16,
    _Float16* __restrict__ VT16)
{
  __shared__ __align__(16) _Float16 Atile[2][128 * 64];   // 2 x 16 KB
  __shared__ __align__(16) _Float16 Btile[2][128 * 64];   // 2 x 16 KB

  int b = blockIdx.x;
  int tid = threadIdx.x, w = tid >> 6, lane = tid & 63, quad = lane >> 4, cL = lane & 15;
  int wr = w >> 1, wc = w & 1;

  const _Float16 *Asrc, *Bsrc;
  int isV;
  int m0 = 0, n0 = 0, head = 0, mh = 0;
  if (b < 256) {
    isV = 0;
    m0 = (b >> 3) * 128;
    int ct = b & 7;
    mh = ct >> 1;                       // 0,1: Q heads; 2,3: K heads
    n0 = (ct & 1) * 128;
    Asrc = h16 + (size_t)m0 * D_IN;
    Bsrc = W6 + (size_t)(ct * 128) * D_IN;
  } else {
    isV = 1;
    int t = b - 256;
    head = t >> 6;
    int tt = t & 63;
    m0 = (tt >> 5) * 128;               // d-half base
    n0 = (tt & 31) * 128;               // token base
    Asrc = Wvt + (size_t)head * (D_HID * D_IN) + (size_t)m0 * D_IN;
    Bsrc = h16 + (size_t)n0 * D_IN;
  }

  const f32x4 z4 = {0.f, 0.f, 0.f, 0.f};
  f32x4 acc[4][4];
#pragma unroll
  for (int i = 0; i < 4; i++)
#pragma unroll
    for (int j = 0; j < 4; j++) acc[i][j] = z4;

  int r8 = lane >> 3, chs = (lane & 7) ^ r8;   // staging row-in-8 / swizzled chunk

  auto stage = [&](int kc, int pb) {
#pragma unroll
    for (int g = 0; g < 4; g++) {
      int row = (w * 4 + g) * 8 + r8;
      async_copy16(Asrc + (size_t)row * D_IN + kc * 64 + chs * 8, Atile[pb] + (w * 4 + g) * 512);
      async_copy16(Bsrc + (size_t)row * D_IN + kc * 64 + chs * 8, Btile[pb] + (w * 4 + g) * 512);
    }
  };

  stage(0, 0);
  __syncthreads();   // drain first tile

  for (int kc = 0; kc < 8; kc++) {
    int cur = kc & 1;
    if (kc + 1 < 8) stage(kc + 1, cur ^ 1);
#pragma unroll
    for (int kk = 0; kk < 2; kk++) {
      int ch = ((kk * 4 + quad) ^ (cL & 7)) * 8;
      half8 a[4], bf[4];
#pragma unroll
      for (int mt = 0; mt < 4; mt++)
        a[mt] = *(const half8*)(Atile[cur] + (wr * 64 + mt * 16 + cL) * 64 + ch);
#pragma unroll
      for (int nt = 0; nt < 4; nt++)
        bf[nt] = *(const half8*)(Btile[cur] + (wc * 64 + nt * 16 + cL) * 64 + ch);
#pragma unroll
      for (int mt = 0; mt < 4; mt++)
#pragma unroll
        for (int nt = 0; nt < 4; nt++)
          acc[mt][nt] = __builtin_amdgcn_mfma_f32_16x16x32_f16(a[mt], bf[nt], acc[mt][nt], 0, 0, 0);
    }
    __syncthreads();   // retire reads of [cur] + drain prefetch DMA into [cur^1]
  }

  if (!isV) {
    _Float16* Out = (mh < 2 ? Q16 + (size_t)mh * (N_TOK * D_HID)
                            : K16 + (size_t)(mh - 2) * (N_TOK * D_HID));
    const float* bias = (mh < 2 ? bq + mh * D_HID : bk + (mh - 2) * D_HID);
#pragma unroll
    for (int mt = 0; mt < 4; mt++) {
      int row = m0 + wr * 64 + mt * 16 + quad * 4;
#pragma unroll
      for (int nt = 0; nt < 4; nt++) {
        int colg = n0 + wc * 64 + nt * 16 + cL;
        float bb = bias[colg];
#pragma unroll
        for (int reg = 0; reg < 4; reg++)
          Out[(size_t)(row + reg) * D_HID + colg] = (_Float16)(acc[mt][nt][reg] + bb);
      }
    }
  } else {
    _Float16* VTh = VT16 + (size_t)head * (N_TOK * D_HID);
    const float* bvh = bv + head * D_HID;
#pragma unroll
    for (int mt = 0; mt < 4; mt++) {
      int d0r = m0 + wr * 64 + mt * 16 + quad * 4;
      float bvv[4];
#pragma unroll
      for (int reg = 0; reg < 4; reg++) bvv[reg] = bvh[d0r + reg];
#pragma unroll
      for (int nt = 0; nt < 4; nt++) {
        int tok = n0 + wc * 64 + nt * 16 + cL;
#pragma unroll
        for (int reg = 0; reg < 4; reg++)
          VTh[(size_t)(d0r + reg) * N_TOK + tok] = (_Float16)(acc[mt][nt][reg] + bvv[reg]);
      }
    }
  }
}

// ---------------------------------------------------------------------------
// attn: flash attention with SWAPPED QK^T (S^T = mfma(K,Q)) so the masked
// online softmax is lane-local (R7 structure, verified). This round: the adj
// prefetch uses 4 x float4 loads (was 16 scalar) and the P->LDS write uses
// 4 x half4 ds_write_b64 (was 16 ds_write_b16) — pure instruction-count cuts,
// no layout/sync/numerics change. 512 thr / 8 waves, grid 256 = 1 block/CU,
// K+V dbuf, one barrier per iteration, setprio around MFMA clusters.
// ---------------------------------------------------------------------------
__global__ __launch_bounds__(512, 2) void attn_kernel(
    const float* __restrict__ adj, const _Float16* __restrict__ Q16,
    const _Float16* __restrict__ K16, const _Float16* __restrict__ VT16,
    _Float16* __restrict__ Opart, float* __restrict__ Mpart, float* __restrict__ Lpart)
{
  __shared__ __align__(16) _Float16 Kt[2][64 * 256];    // 2 x 32 KB  [key][d]
  __shared__ __align__(16) _Float16 Vt[2][256 * 64];    // 2 x 32 KB  [d][tok]
  __shared__ __align__(16) _Float16 Pbuf[8 * 16 * 72];  // 18 KB

  int b = blockIdx.x;
  int head = (b >> 2) & 1;
  int gs = b & 3;
  int q0 = (b >> 3) * 128;

  int tid = threadIdx.x;
  int w = tid >> 6, lane = tid & 63, quad = lane >> 4, cL = lane & 15;

  const _Float16* Qh = Q16 + head * (N_TOK * D_HID);
  const _Float16* Kh = K16 + head * (N_TOK * D_HID);
  const _Float16* Vh = VT16 + head * (N_TOK * D_HID);
  const float* adjh = adj + (size_t)head * N_TOK * N_TOK;

  int qrow = q0 + w * 16;
  int nstart = gs * 1024;
  const f32x4 z4 = {0.f, 0.f, 0.f, 0.f};

  half8 qf[8];
#pragma unroll
  for (int t = 0; t < 8; t++)
    qf[t] = *(const half8*)(Qh + (qrow + cL) * D_HID + t * 32 + quad * 8);

  f32x4 acc[16];
#pragma unroll
  for (int i = 0; i < 16; i++) acc[i] = z4;
  float m_q = -1e30f;   // running max for row q=cL (replicated across quads)
  float l_q = 0.f;      // running sum for row q=cL

  _Float16* pb = Pbuf + w * (16 * 72);

  // adj: lane (cL,quad) needs adj[qrow+cL][n + ct*16 + quad*4 + reg] —
  // reg 0..3 consecutive, 16B aligned -> float4.
  const float* adjRT = adjh + (size_t)(qrow + cL) * N_TOK + nstart + quad * 4;

  int l5 = lane >> 5, l31 = lane & 31;   // K staging: 2 rows (512B) per copy
  int l3 = lane >> 3, l7 = lane & 7;     // V staging: 8 rows (128B) per copy

  // stage K tile (64 keys x 256 d); xor-swizzled 16B chunks in 512B rows.
  auto stageK = [&](int it, _Float16* dst) {
    int n0 = nstart + it * 64;
#pragma unroll
    for (int i = 0; i < 4; i++) {
      int g = w * 4 + i;
      int rK = 2 * g + l5;
      int cK = l31 ^ (rK & 7);
      async_copy16(Kh + (size_t)(n0 + rK) * D_HID + cK * 8, dst + g * 512);
    }
  };
  // stage V tile (256 d x 64 tok); xor-swizzled 16B chunks in 128B rows.
  auto stageV = [&](int it, _Float16* dst) {
    int n0 = nstart + it * 64;
#pragma unroll
    for (int i = 0; i < 4; i++) {
      int g = w * 4 + i;
      int rV = g * 8 + l3;
      int cV = l7 ^ (rV & 7);
      async_copy16(Vh + (size_t)rV * N_TOK + n0 + cV * 8, dst + g * 512);
    }
  };
  auto loadAdj = [&](int it, f32x4 (&av)[4]) {
#pragma unroll
    for (int ct = 0; ct < 4; ct++)
      av[ct] = __builtin_nontemporal_load((const f32x4*)(adjRT + it * 64 + ct * 16));
  };

  auto body = [&](int it, const _Float16* KC, const _Float16* VC,
                  _Float16* KN, _Float16* VN,
                  f32x4 (&avC)[4], f32x4 (&avN)[4]) {
    // prefetch tile it+1 (K+V DMA + adj) before any compute on tile it
    if (it + 1 < 16) {
      stageK(it + 1, KN);
      stageV(it + 1, VN);
      loadAdj(it + 1, avN);
    }

    // QK^T swapped: sT[ct] = mfma(K, Q) -> lane holds S[q=cL][k=ct*16+quad*4+reg]
    f32x4 sT[4];
#pragma unroll
    for (int ct = 0; ct < 4; ct++) sT[ct] = z4;
    __builtin_amdgcn_s_setprio(1);
#pragma unroll
    for (int t = 0; t < 8; t++) {
#pragma unroll
      for (int ct = 0; ct < 4; ct++) {
        int rK = ct * 16 + cL;
        int ck = (t * 4 + quad) ^ (rK & 7);
        half8 kf = *(const half8*)(KC + rK * 256 + ck * 8);
        sT[ct] = __builtin_amdgcn_mfma_f32_16x16x32_f16(kf, qf[t], sT[ct], 0, 0, 0);
      }
    }
    __builtin_amdgcn_s_setprio(0);

    // mask + lane-local row max over the 16 in-register k-values
    float mrow = -1e30f;
#pragma unroll
    for (int ct = 0; ct < 4; ct++)
#pragma unroll
      for (int reg = 0; reg < 4; reg++) {
        float v = sT[ct][reg] * avC[ct][reg];
        sT[ct][reg] = v;
        mrow = fmaxf(mrow, v);
      }
    // cross-quad reduce (lanes sharing cL): 2 rounds
    mrow = fmaxf(mrow, __shfl_xor(mrow, 16, 64));
    mrow = fmaxf(mrow, __shfl_xor(mrow, 32, 64));

    float mnew = fmaxf(m_q, mrow);
    float alpha = __expf(m_q - mnew);
    m_q = mnew;

    float rs = 0.f;
#pragma unroll
    for (int ct = 0; ct < 4; ct++)
#pragma unroll
      for (int reg = 0; reg < 4; reg++) {
        float p = __expf(sT[ct][reg] - mnew);
        sT[ct][reg] = p;
        rs += p;
      }
    rs += __shfl_xor(rs, 16, 64);
    rs += __shfl_xor(rs, 32, 64);
    l_q = l_q * alpha + rs;

    // P -> LDS as [q=cL][k]; 4 x half4 packed writes (8B, 2-way-conflict-free)
#pragma unroll
    for (int ct = 0; ct < 4; ct++) {
      half4 pk;
#pragma unroll
      for (int reg = 0; reg < 4; reg++) pk[reg] = (_Float16)sT[ct][reg];
      *(half4*)(pb + cL * 72 + ct * 16 + quad * 4) = pk;
    }

    // rescale acc only if any row's max grew; acc rows are q=quad*4+reg, so
    // fetch alpha from the lane holding that q (same quad group, cL=q).
    if (__any(alpha != 1.0f)) {
      float alphaA[4];
#pragma unroll
      for (int reg = 0; reg < 4; reg++)
        alphaA[reg] = __shfl(alpha, (lane & 48) | (quad * 4 + reg), 64);
#pragma unroll
      for (int dt = 0; dt < 16; dt++)
#pragma unroll
        for (int reg = 0; reg < 4; reg++)
          acc[dt][reg] *= alphaA[reg];
    }

    // PV : acc[q][d] += P[q][k] * V[d][k]  (unchanged)
    half8 pf0 = *(const half8*)(pb + cL * 72 + quad * 8);
    half8 pf1 = *(const half8*)(pb + cL * 72 + 32 + quad * 8);
    __builtin_amdgcn_s_setprio(1);
#pragma unroll
    for (int dt = 0; dt < 16; dt++) {
      int rV = dt * 16 + cL;
      int c0 = (quad) ^ (rV & 7);
      int c1 = (4 + quad) ^ (rV & 7);
      half8 v0 = *(const half8*)(VC + rV * 64 + c0 * 8);
      half8 v1 = *(const half8*)(VC + rV * 64 + c1 * 8);
      acc[dt] = __builtin_amdgcn_mfma_f32_16x16x32_f16(pf0, v0, acc[dt], 0, 0, 0);
      acc[dt] = __builtin_amdgcn_mfma_f32_16x16x32_f16(pf1, v1, acc[dt], 0, 0, 0);
    }
    __builtin_amdgcn_s_setprio(0);

    // single barrier: drains prefetch DMA (vmcnt 0) + retires KC/VC reads
    // before the next iteration's stage overwrites them.
    __syncthreads();
  };

  // prologue: tile 0 into buffer 0
  stageK(0, Kt[0]);
  stageV(0, Vt[0]);
  f32x4 avA[4], avB[4];
  loadAdj(0, avA);
  __syncthreads();

  for (int itp = 0; itp < 8; ++itp) {
    body(2 * itp,     Kt[0], Vt[0], Kt[1], Vt[1], avA, avB);
    body(2 * itp + 1, Kt[1], Vt[1], Kt[0], Vt[0], avB, avA);
  }

  int prowbase = (head * 4 + gs) * N_TOK + qrow;
#pragma unroll
  for (int reg = 0; reg < 4; reg++) {
    int row = prowbase + quad * 4 + reg;
#pragma unroll
    for (int dt = 0; dt < 16; dt++)
      Opart[(size_t)row * D_HID + dt * 16 + cL] = (_Float16)acc[dt][reg];
  }
  // m/l live per-lane for q=cL (replicated across quads): quad 0 writes.
  if (quad == 0) {
    Mpart[prowbase + cL] = m_q;
    Lpart[prowbase + cL] = l_q;
  }
}

// ---------------------------------------------------------------------------
// final (fused with merge): per 16-row block. The 8 Opart slabs for this
// row-block are staged COALESCED into LDS, then each thread gathers its af[]
// fragments from LDS with the split weights. Then z = X@Wo + bo -> LayerNorm
// -> softmax(M@Wp + bp) -> out [4096][40]. grid 256 x 256 thr. LDS ~150 KB.
// ---------------------------------------------------------------------------
__global__ __launch_bounds__(256, 1) void final_kernel(
    const _Float16* __restrict__ Opart, const float* __restrict__ Mpart,
    const float* __restrict__ Lpart, const _Float16* __restrict__ Wot,
    const _Float16* __restrict__ Wpt, const float* __restrict__ bo,
    const float* __restrict__ gamma, const float* __restrict__ beta,
    const float* __restrict__ bp, float* __restrict__ out)
{
  __shared__ __align__(16) _Float16 Btile[512 * 64];      // 64 KB
  __shared__ __align__(16) _Float16 Ostage[8 * 16 * 264]; // 66 KB (rows padded to 264)
  __shared__ __align__(16) _Float16 Mlds[16 * 520];
  __shared__ float outs[16 * 48];
  __shared__ float lnsum[4][16], lnsq[4][16];
  __shared__ float smx[16], srl[16];

  int rowbase = blockIdx.x * 16;
  int tid = threadIdx.x, w = tid >> 6, lane = tid & 63, quad = lane >> 4, cL = lane & 15;
  const f32x4 z4 = {0.f, 0.f, 0.f, 0.f};
  int row = rowbase + cL;

  // ---- stage the 8 Opart slabs (split-major) coalesced into LDS.
#pragma unroll
  for (int i = 0; i < 16; i++) {
    int u = tid + 256 * i;
    int sl = u >> 9;            // 0..7 = head*4 + split
    int r  = (u >> 5) & 15;     // row within slab
    int c8 = u & 31;            // 16B column unit
    half8 v = *(const half8*)(Opart + (size_t)(sl * N_TOK + rowbase + r) * D_HID + c8 * 8);
    *(half8*)(Ostage + (sl * 16 + r) * 264 + c8 * 8) = v;
  }

  // ---- merge weights: per-head split weights f[s]*rl for this thread's row
  float fr[2][4];
#pragma unroll
  for (int hd = 0; hd < 2; hd++) {
    float m[4], l[4];
    float mm = -1e30f;
#pragma unroll
    for (int s = 0; s < 4; s++) {
      int idx = (hd * 4 + s) * N_TOK + row;
      m[s] = Mpart[idx];
      l[s] = Lpart[idx];
      mm = fmaxf(mm, m[s]);
    }
    float f_[4], L = 0.f;
#pragma unroll
    for (int s = 0; s < 4; s++) { f_[s] = __expf(m[s] - mm); L += f_[s] * l[s]; }
    float rl = 1.0f / L;
#pragma unroll
    for (int s = 0; s < 4; s++) fr[hd][s] = f_[s] * rl;
  }

  __syncthreads();   // Ostage visible to all

  // ---- A-fragments: af[t] = X[row][t*32 + quad*8 .. +8] merged from 4 splits
  half8 af[16];
#pragma unroll
  for (int t = 0; t < 16; t++) {
    int hd = t >> 3;                       // col = hd*256 + dg
    int dg = (t & 7) * 32 + quad * 8;
    float o[8] = {0.f, 0.f, 0.f, 0.f, 0.f, 0.f, 0.f, 0.f};
#pragma unroll
    for (int s = 0; s < 4; s++) {
      half8 os = *(const half8*)(Ostage + ((hd * 4 + s) * 16 + cL) * 264 + dg);
#pragma unroll
      for (int u = 0; u < 8; u++) o[u] += (float)os[u] * fr[hd][s];
    }
#pragma unroll
    for (int u = 0; u < 8; u++) af[t][u] = (_Float16)o[u];
  }

  f32x4 acc[8];
#pragma unroll
  for (int i = 0; i < 8; i++) acc[i] = z4;

  int r8 = lane >> 3, chs = (lane & 7) ^ r8;

  for (int kc = 0; kc < 8; kc++) {
    __syncthreads();
#pragma unroll
    for (int g = 0; g < 16; g++) {
      int grow = (w * 16 + g) * 8 + r8;
      async_copy16(Wot + (size_t)grow * D_IN + kc * 64 + chs * 8, Btile + (w * 16 + g) * 512);
    }
    __syncthreads();
#pragma unroll
    for (int kk = 0; kk < 2; kk++) {
      int ch = ((kk * 4 + quad) ^ (cL & 7)) * 8;
      half8 a = af[kc * 2 + kk];
      half8 bf[8];
#pragma unroll
      for (int nt = 0; nt < 8; nt++)
        bf[nt] = *(const half8*)(Btile + (w * 128 + nt * 16 + cL) * 64 + ch);
#pragma unroll
      for (int nt = 0; nt < 8; nt++)
        acc[nt] = __builtin_amdgcn_mfma_f32_16x16x32_f16(a, bf[nt], acc[nt], 0, 0, 0);
    }
  }

  float sum[4] = {0, 0, 0, 0}, sq[4] = {0, 0, 0, 0};
#pragma unroll
  for (int nt = 0; nt < 8; nt++) {
    int col = w * 128 + nt * 16 + cL;
    float bb = bo[col];
#pragma unroll
    for (int reg = 0; reg < 4; reg++) {
      float z = acc[nt][reg] + bb;
      acc[nt][reg] = z;
      sum[reg] += z;
      sq[reg] += z * z;
    }
  }
#pragma unroll
  for (int reg = 0; reg < 4; reg++) {
#pragma unroll
    for (int msk = 1; msk < 16; msk <<= 1) {
      sum[reg] += __shfl_xor(sum[reg], msk, 16);
      sq[reg]  += __shfl_xor(sq[reg], msk, 16);
    }
  }
  if (cL == 0) {
#pragma unroll
    for (int reg = 0; reg < 4; reg++) {
      lnsum[w][quad * 4 + reg] = sum[reg];
      lnsq[w][quad * 4 + reg]  = sq[reg];
    }
  }
  __syncthreads();
  float mean[4], rstd[4];
#pragma unroll
  for (int reg = 0; reg < 4; reg++) {
    int r = quad * 4 + reg;
    float s  = lnsum[0][r] + lnsum[1][r] + lnsum[2][r] + lnsum[3][r];
    float s2 = lnsq[0][r]  + lnsq[1][r]  + lnsq[2][r]  + lnsq[3][r];
    float mu = s * (1.0f / 512.0f);
    float var = s2 * (1.0f / 512.0f) - mu * mu;
    mean[reg] = mu;
    rstd[reg] = rsqrtf(var + 1e-5f);
  }
#pragma unroll
  for (int nt = 0; nt < 8; nt++) {
    int col = w * 128 + nt * 16 + cL;
    float g = gamma[col], be = beta[col];
#pragma unroll
    for (int reg = 0; reg < 4; reg++) {
      float mval = (acc[nt][reg] - mean[reg]) * rstd[reg] * g + be;
      Mlds[(quad * 4 + reg) * 520 + col] = (_Float16)mval;
    }
  }
  __syncthreads();
  if (w < 3) {
    int jt = w;
    f32x4 a2 = z4;
#pragma unroll
    for (int t = 0; t < 16; t++) {
      half8 am = *(const half8*)(Mlds + cL * 520 + t * 32 + quad * 8);
      half8 bm = *(const half8*)(Wpt + (jt * 16 + cL) * D_IN + t * 32 + quad * 8);
      a2 = __builtin_amdgcn_mfma_f32_16x16x32_f16(am, bm, a2, 0, 0, 0);
    }
    int col = jt * 16 + cL;
    float bpv = (col < N_OUT) ? bp[col] : 0.0f;
#pragma unroll
    for (int reg = 0; reg < 4; reg++)
      outs[(quad * 4 + reg) * 48 + col] = a2[reg] + bpv;
  }
  __syncthreads();
  if (tid < 16) {
    int r = tid;
    float mx = -1e30f;
    for (int j = 0; j < N_OUT; j++) mx = fmaxf(mx, outs[r * 48 + j]);
    float ssum = 0.f;
    for (int j = 0; j < N_OUT; j++) ssum += __expf(outs[r * 48 + j] - mx);
    smx[r] = mx;
    srl[r] = 1.0f / ssum;
  }
  __syncthreads();
#pragma unroll
  for (int i = 0; i < 3; i++) {
    int lin = tid + 256 * i;
    if (lin < 16 * N_OUT) {
      int r = lin / N_OUT, col = lin % N_OUT;
      out[(size_t)(rowbase + r) * N_OUT + col] =
          __expf(outs[r * 48 + col] - smx[r]) * srl[r];
    }
  }
}

// ---------------------------------------------------------------------------
// Workspace layout (bytes, 256-aligned). Opart overlays buffers dead by attn
// time (h16, Wqt/Wkt/Wvt). V16 eliminated (VT computed directly in proj).
// Xf eliminated (merge fused into final).
// ---------------------------------------------------------------------------
#define OFF_WOT   0u
#define OFF_WPT   524288u
#define OFF_Q16   573440u
#define OFF_K16   4767744u
#define OFF_VT16  8962048u
#define OFF_MP    13156352u
#define OFF_LP    13287424u
#define OFF_OP    17612800u
// overlay (dead before attn):
#define OFF_H16   17612800u
#define OFF_WQT   21807104u
#define OFF_WKT   22331392u
#define OFF_WVT   22855680u

extern "C" void kernel_launch(void* const* d_in, const int* in_sizes, int n_in,
                              void* d_out, int out_size, void* d_ws, size_t ws_size,
                              hipStream_t stream)
{
  const float* adj   = (const float*)d_in[0];
  const float* h     = (const float*)d_in[1];
  const float* Wq    = (const float*)d_in[2];
  const float* bq    = (const float*)d_in[3];
  const float* Wk    = (const float*)d_in[4];
  const float* bk    = (const float*)d_in[5];
  const float* Wv    = (const float*)d_in[6];
  const float* bv    = (const float*)d_in[7];
  const float* Wo    = (const float*)d_in[8];
  const float* bo    = (const float*)d_in[9];
  const float* gamma = (const float*)d_in[10];
  const float* beta  = (const float*)d_in[11];
  const float* Wp    = (const float*)d_in[12];
  const float* bp    = (const float*)d_in[13];
  float* out = (float*)d_out;
  char* ws = (char*)d_ws;

  _Float16* h16   = (_Float16*)(ws + OFF_H16);
  _Float16* Wqt   = (_Float16*)(ws + OFF_WQT);
  _Float16* Wkt   = (_Float16*)(ws + OFF_WKT);
  _Float16* Wvt   = (_Float16*)(ws + OFF_WVT);
  _Float16* Wot   = (_Float16*)(ws + OFF_WOT);
  _Float16* Wpt   = (_Float16*)(ws + OFF_WPT);
  _Float16* Q16   = (_Float16*)(ws + OFF_Q16);
  _Float16* K16   = (_Float16*)(ws + OFF_K16);
  _Float16* VT16  = (_Float16*)(ws + OFF_VT16);
  _Float16* Opart = (_Float16*)(ws + OFF_OP);
  float*    Mpart = (float*)(ws + OFF_MP);
  float*    Lpart = (float*)(ws + OFF_LP);

  prep_kernel<<<1304, 256, 0, stream>>>(h, Wq, Wk, Wv, Wo, Wp,
                                        h16, Wqt, Wkt, Wvt, Wot, Wpt);
  proj_kernel<<<384, 256, 0, stream>>>(h16, Wqt, Wvt, bq, bk, bv,
                                       Q16, K16, VT16);
  attn_kernel<<<256, 512, 0, stream>>>(adj, Q16, K16, VT16, Opart, Mpart, Lpart);
  final_kernel<<<256, 256, 0, stream>>>(Opart, Mpart, Lpart, Wot, Wpt,
                                        bo, gamma, beta, bp, out);
}